// Round 6
// baseline (475.244 us; speedup 1.0000x reference)
//
#include <hip/hip_runtime.h>
#include <hip/hip_bf16.h>
#include <math.h>

#define B_ 2
#define S_ 2048
#define H_ 512
#define NH_ 8
#define HD_ 64
#define L_ 4
#define INTER_ 2048
#define W1_ 32
#define WB_ 65
#define M_ (B_*S_)   // 4096

typedef __attribute__((ext_vector_type(8))) short short8v;
typedef __attribute__((ext_vector_type(4))) float f32x4;

__device__ __forceinline__ float b2f(ushort u){ return __uint_as_float(((unsigned)u)<<16); }
__device__ __forceinline__ ushort f2b(float f){
  unsigned u = __float_as_uint(f);
  unsigned r = (u + 0x7fffu + ((u>>16)&1u)) >> 16;
  return (ushort)r;
}

// async global->LDS, 16B per lane (linear LDS dest = base + lane*16).
__device__ __forceinline__ void async16(const ushort* g, ushort* l){
  __builtin_amdgcn_global_load_lds(
      (const __attribute__((address_space(1))) unsigned int*)g,
      (__attribute__((address_space(3))) unsigned int*)l, 16, 0, 0);
}

// ---------------------------------------------------------------- transpose+cvt
// src [R][C] f32 row-major -> dst [C][R] bf16 row-major (batched over z)
__global__ __launch_bounds__(256) void transpose_k(const float* __restrict__ src,
    ushort* __restrict__ dst, int R, int C, size_t sBatch, size_t dBatch)
{
  __shared__ ushort tile[32][33];
  src += (size_t)blockIdx.z * sBatch;
  dst += (size_t)blockIdx.z * dBatch;
  int tx = threadIdx.x & 31, ty = threadIdx.x >> 5;   // 32 x 8
  int r0 = blockIdx.y * 32, c0 = blockIdx.x * 32;
  #pragma unroll
  for (int i = 0; i < 4; ++i){
    int r = r0 + ty + i*8;
    tile[ty + i*8][tx] = f2b(src[(size_t)r * C + c0 + tx]);
  }
  __syncthreads();
  #pragma unroll
  for (int i = 0; i < 4; ++i){
    int c = c0 + ty + i*8;
    dst[(size_t)c * R + r0 + tx] = tile[tx][ty + i*8];
  }
}

__global__ __launch_bounds__(256) void pack_bqkv(const float* __restrict__ bq,
    const float* __restrict__ bk, const float* __restrict__ bv, float* __restrict__ dst)
{
  int i = blockIdx.x * 256 + threadIdx.x;      // < L_*1536
  int l = i / 1536, n = i % 1536;
  float v = (n < 512) ? bq[l*512 + n] : (n < 1024 ? bk[l*512 + n - 512] : bv[l*512 + n - 1024]);
  dst[i] = v;
}

// ---------------------------------------------------------------- GEMM (B^T)
// C[M,N] = A[M,K(part)] @ Bt[N,K]^T (+ bias on z==0)
// EPI: 0=bf16, 1=gelu->bf16, 2=tanh->bf16, 3=f32 (split-K partial at z*M*N)
// BM=128, BN=128, BK=32; 4 waves, 4x4 acc; double-buffered global_load_lds.
template<int EPI>
__global__ __launch_bounds__(256) void gemm_bt(
    const ushort* __restrict__ A, const ushort* __restrict__ Bt,
    const float* __restrict__ bias, ushort* __restrict__ o16,
    float* __restrict__ o32, int M, int N, int K, int Klen)
{
  __shared__ ushort lds_a[2][128][32];   // 16 KB
  __shared__ ushort lds_b[2][128][32];   // 16 KB
  const int tid = threadIdx.x;
  const int bm = blockIdx.y * 128, bn = blockIdx.x * 128;
  const int kbeg = blockIdx.z * Klen;
  const int wave = tid >> 6, lane = tid & 63;
  const int wr = (wave >> 1) * 64, wc = (wave & 1) * 64;
  const int lr = lane & 15, lg = lane >> 4, lk = lg * 8;
  f32x4 acc[4][4] = {};

  // staging: 2 rounds for A, 2 for B; round r covers rows r*64 + (tid>>2)
  const ushort* Ag = A  + (size_t)(bm + (tid >> 2)) * K + kbeg + (tid & 3) * 8;
  const ushort* Bg = Bt + (size_t)(bn + (tid >> 2)) * K + kbeg + (tid & 3) * 8;
  ushort* la = &lds_a[0][0][0] + tid * 8;   // +4096 per buffer, +2048 per round
  ushort* lb = &lds_b[0][0][0] + tid * 8;

  const int nIter = Klen >> 5;
  // prologue: stage tile 0 into buf 0
  async16(Ag,            la);
  async16(Ag + 64 * K,   la + 2048);
  async16(Bg,            lb);
  async16(Bg + 64 * K,   lb + 2048);
  __syncthreads();

  int cur = 0;
  for (int t = 0; t < nIter; ++t){
    if (t + 1 < nIter){                  // prefetch next tile into buf cur^1
      int k0 = (t + 1) << 5;
      int nb = cur ^ 1;
      async16(Ag + k0,          la + nb*4096);
      async16(Ag + 64*K + k0,   la + nb*4096 + 2048);
      async16(Bg + k0,          lb + nb*4096);
      async16(Bg + 64*K + k0,   lb + nb*4096 + 2048);
    }
    short8v af[4], bfr[4];
    #pragma unroll
    for (int mi = 0; mi < 4; ++mi)
      af[mi] = *(const short8v*)(&lds_a[cur][wr + mi*16 + lr][lk]);
    #pragma unroll
    for (int nj = 0; nj < 4; ++nj)
      bfr[nj] = *(const short8v*)(&lds_b[cur][wc + nj*16 + lr][lk]);
    #pragma unroll
    for (int mi = 0; mi < 4; ++mi)
      #pragma unroll
      for (int nj = 0; nj < 4; ++nj)
        acc[mi][nj] = __builtin_amdgcn_mfma_f32_16x16x32_bf16(af[mi], bfr[nj], acc[mi][nj], 0, 0, 0);
    __syncthreads();                     // drains prefetch vmcnt + guards reuse
    cur ^= 1;
  }

  const float bscale = (blockIdx.z == 0) ? 1.0f : 0.0f;
  #pragma unroll
  for (int mi = 0; mi < 4; ++mi){
    #pragma unroll
    for (int nj = 0; nj < 4; ++nj){
      int col = bn + wc + nj*16 + lr;
      float bv = bias[col] * bscale;
      #pragma unroll
      for (int j = 0; j < 4; ++j){
        int row = bm + wr + mi*16 + lg*4 + j;
        float v = acc[mi][nj][j] + bv;
        if (EPI == 1) v = 0.5f * v * (1.0f + erff(v * 0.70710678118654752f));
        if (EPI == 2) v = tanhf(v);
        if (EPI == 3) o32[(size_t)blockIdx.z*M*N + (size_t)row * N + col] = v;
        else          o16[(size_t)row * N + col] = f2b(v);
      }
    }
  }
}

// ---------------------------------------------------------------- fused Wo GEMM + residual + LN
// out = LN(A @ Bt^T + bias + res).  BM=16, BN=512 (full row), K=512.
// 4 waves; wave w covers cols w*128; grid = M/16 = 256 blocks.
__global__ __launch_bounds__(256) void gemm_wo_ln(
    const ushort* __restrict__ A, const ushort* __restrict__ Bt,
    const float* __restrict__ bias, const float* __restrict__ res,
    const float* __restrict__ g, const float* __restrict__ bb,
    ushort* __restrict__ out16, float* __restrict__ out32)
{
  __shared__ ushort lds_a[2][16][32];    // 2 KB
  __shared__ ushort lds_b[2][512][32];   // 64 KB
  __shared__ float  red[4][2][16];

  const int tid = threadIdx.x;
  const int bm = blockIdx.x * 16;
  const int wave = tid >> 6, lane = tid & 63;
  const int wc = wave * 128;
  const int lr = lane & 15, lg = lane >> 4, lk = lg * 8;
  f32x4 acc[8] = {};

  const ushort* Ag = A  + (size_t)(bm + (tid >> 2)) * 512 + (tid & 3) * 8;   // tid<64 only
  const ushort* Bg = Bt + (size_t)(tid >> 2) * 512 + (tid & 3) * 8;          // +r*64 rows
  ushort* la = &lds_a[0][0][0] + tid * 8;     // buffer stride 512
  ushort* lb = &lds_b[0][0][0] + tid * 8;     // buffer stride 16384, round stride 2048

  // prologue: stage tile 0
  if (tid < 64) async16(Ag, la);
  #pragma unroll
  for (int r = 0; r < 8; ++r) async16(Bg + (size_t)r*64*512, lb + r*2048);
  __syncthreads();

  int cur = 0;
  for (int t = 0; t < 16; ++t){
    if (t < 15){
      int k0 = (t + 1) * 32;
      int nb = cur ^ 1;
      if (tid < 64) async16(Ag + k0, la + nb*512);
      #pragma unroll
      for (int r = 0; r < 8; ++r)
        async16(Bg + (size_t)r*64*512 + k0, lb + nb*16384 + r*2048);
    }
    short8v af = *(const short8v*)(&lds_a[cur][lr][lk]);
    #pragma unroll
    for (int nj = 0; nj < 8; ++nj){
      short8v bf = *(const short8v*)(&lds_b[cur][wc + nj*16 + lr][lk]);
      acc[nj] = __builtin_amdgcn_mfma_f32_16x16x32_bf16(af, bf, acc[nj], 0, 0, 0);
    }
    __syncthreads();
    cur ^= 1;
  }

  // epilogue: v = acc + bias + res; LN over full 512-wide rows
  float vv[8][4];
  float sm[4] = {0,0,0,0}, sq[4] = {0,0,0,0};
  #pragma unroll
  for (int nj = 0; nj < 8; ++nj){
    int col = wc + nj*16 + lr;
    float bv = bias[col];
    #pragma unroll
    for (int j = 0; j < 4; ++j){
      int grow = bm + lg*4 + j;
      float v = acc[nj][j] + bv + res[(size_t)grow*512 + col];
      vv[nj][j] = v;
      sm[j] += v;
      sq[j] += v*v;
    }
  }
  #pragma unroll
  for (int o = 1; o < 16; o <<= 1){
    #pragma unroll
    for (int j = 0; j < 4; ++j){
      sm[j] += __shfl_xor(sm[j], o);
      sq[j] += __shfl_xor(sq[j], o);
    }
  }
  if (lr == 0){
    #pragma unroll
    for (int j = 0; j < 4; ++j){
      red[wave][0][lg*4 + j] = sm[j];
      red[wave][1][lg*4 + j] = sq[j];
    }
  }
  __syncthreads();
  float mean[4], rstd[4];
  #pragma unroll
  for (int j = 0; j < 4; ++j){
    int R = lg*4 + j;
    float S = red[0][0][R] + red[1][0][R] + red[2][0][R] + red[3][0][R];
    float Q = red[0][1][R] + red[1][1][R] + red[2][1][R] + red[3][1][R];
    mean[j] = S * (1.0f / 512.0f);
    float var = Q * (1.0f / 512.0f) - mean[j]*mean[j];
    if (var < 0.f) var = 0.f;
    rstd[j] = rsqrtf(var + 1e-12f);
  }
  #pragma unroll
  for (int nj = 0; nj < 8; ++nj){
    int col = wc + nj*16 + lr;
    float gv = g[col], bbv = bb[col];
    #pragma unroll
    for (int j = 0; j < 4; ++j){
      int grow = bm + lg*4 + j;
      float o = (vv[nj][j] - mean[j]) * rstd[j] * gv + bbv;
      out16[(size_t)grow*512 + col] = f2b(o);
      out32[(size_t)grow*512 + col] = o;
    }
  }
}

// ---------------------------------------------------------------- LayerNorm
__device__ __forceinline__ void block_ln_stats(float v0, float v1, float* red,
                                               float& mean, float& rstd)
{
  int tid = threadIdx.x, wave = tid >> 6, lane = tid & 63;
  float sm = v0 + v1;
  float sq = v0*v0 + v1*v1;
  #pragma unroll
  for (int o = 32; o > 0; o >>= 1){ sm += __shfl_xor(sm, o); sq += __shfl_xor(sq, o); }
  if (lane == 0){ red[wave] = sm; red[4 + wave] = sq; }
  __syncthreads();
  float S = red[0] + red[1] + red[2] + red[3];
  float Q = red[4] + red[5] + red[6] + red[7];
  mean = S * (1.0f / 512.0f);
  float var = Q * (1.0f / 512.0f) - mean*mean;
  if (var < 0.f) var = 0.f;
  rstd = rsqrtf(var + 1e-12f);
}

// embeddings LN: x,pos f32 -> out bf16 + f32 shadow
__global__ __launch_bounds__(256) void embed_ln(const float* __restrict__ x,
    const float* __restrict__ pos, const float* __restrict__ g,
    const float* __restrict__ bb, ushort* __restrict__ out16, float* __restrict__ out32)
{
  __shared__ float red[8];
  int row = blockIdx.x, tid = threadIdx.x;
  int s = row & (S_ - 1);
  float v0 = x[(size_t)row*H_ + tid]       + pos[(size_t)s*H_ + tid];
  float v1 = x[(size_t)row*H_ + tid + 256] + pos[(size_t)s*H_ + tid + 256];
  float mean, rstd;
  block_ln_stats(v0, v1, red, mean, rstd);
  float r0 = (v0 - mean)*rstd*g[tid]       + bb[tid];
  float r1 = (v1 - mean)*rstd*g[tid + 256] + bb[tid + 256];
  out16[(size_t)row*H_ + tid]       = f2b(r0);
  out16[(size_t)row*H_ + tid + 256] = f2b(r1);
  out32[(size_t)row*H_ + tid]       = r0;
  out32[(size_t)row*H_ + tid + 256] = r1;
}

// LN(t0 + t1 + res32): two split-K f32 partials + f32 residual -> bf16 + f32 shadow
__global__ __launch_bounds__(256) void ln_res(const float* __restrict__ t,
    const float* __restrict__ res, const float* __restrict__ g,
    const float* __restrict__ bb, ushort* __restrict__ out16, float* __restrict__ out32)
{
  __shared__ float red[8];
  int row = blockIdx.x, tid = threadIdx.x;
  const size_t MN = (size_t)M_*H_;
  float v0 = t[(size_t)row*H_ + tid]       + t[MN + (size_t)row*H_ + tid]
           + res[(size_t)row*H_ + tid];
  float v1 = t[(size_t)row*H_ + tid + 256] + t[MN + (size_t)row*H_ + tid + 256]
           + res[(size_t)row*H_ + tid + 256];
  float mean, rstd;
  block_ln_stats(v0, v1, red, mean, rstd);
  float r0 = (v0 - mean)*rstd*g[tid]       + bb[tid];
  float r1 = (v1 - mean)*rstd*g[tid + 256] + bb[tid + 256];
  out16[(size_t)row*H_ + tid]       = f2b(r0);
  out16[(size_t)row*H_ + tid + 256] = f2b(r1);
  out32[(size_t)row*H_ + tid]       = r0;
  out32[(size_t)row*H_ + tid + 256] = r1;
}

// ---------------------------------------------------------------- attention (MFMA)
// qkv: [B*S][1536] bf16 (q|k|v each 512). Block: 256 thr (4 waves) = one
// (b,h) x 64-row Q-block. Keys/values: 128-wide chunk [s0-32, s0+95].
__global__ __launch_bounds__(256) void attn_mfma(const ushort* __restrict__ qkv,
    const float* __restrict__ mask, ushort* __restrict__ ctx)
{
  __shared__ ushort K_lds[128][72];   // [key c][k]   (pad 72: 2-way free)
  __shared__ ushort Vt[64][136];      // [d][key c]   (pad 136)
  __shared__ ushort P_lds[64][136];   // [q row][key c]
  __shared__ float  kb[128];

  const int tid = threadIdx.x, wave = tid >> 6, lane = tid & 63;
  const int hh = blockIdx.y & (NH_ - 1), b = blockIdx.y >> 3;
  const int s0 = blockIdx.x * 64;
  const size_t rb = (size_t)b * S_;

  // ---- stage K rows c=0..127 and V^T
  const int ch = tid & 7;             // 16B chunk within 64-d row
  const int rr = tid >> 3;            // 0..31
  #pragma unroll
  for (int it = 0; it < 4; ++it){
    int c = rr + it*32;
    int j = s0 - 32 + c;
    int jc = min(max(j, 0), S_ - 1);
    const size_t rowb = (rb + jc) * 1536 + hh*64 + ch*8;
    *(short8v*)(&K_lds[c][ch*8]) = *(const short8v*)(qkv + rowb + 512);
    short8v vv = *(const short8v*)(qkv + rowb + 1024);
    #pragma unroll
    for (int t = 0; t < 8; ++t){      // staggered transpose write (<=2-way)
      int tt = (t + ch) & 7;
      Vt[ch*8 + tt][c] = (ushort)vv[tt];
    }
  }
  if (tid < 128){
    int j = s0 - 32 + tid;
    kb[tid] = (j >= 0 && j < S_) ? (1.0f - mask[rb + j]) * (-10000.0f) : -1e30f;
  }
  __syncthreads();

  const int wq0 = wave * 16;
  const int lr = lane & 15, lg = lane >> 4, lk = lg * 8;

  // Q fragments (A): row = wq0+lr, k = lk..lk+7 (+32 for second frag)
  const ushort* qbase = qkv + (rb + s0 + wq0 + lr) * 1536 + hh*64;
  short8v aq0 = *(const short8v*)(qbase + lk);
  short8v aq1 = *(const short8v*)(qbase + 32 + lk);

  // scores: 16x128 strip per wave
  f32x4 sacc[8];
  #pragma unroll
  for (int cn = 0; cn < 8; ++cn){
    short8v bk0 = *(const short8v*)(&K_lds[cn*16 + lr][lk]);
    short8v bk1 = *(const short8v*)(&K_lds[cn*16 + lr][32 + lk]);
    f32x4 z = {0.f, 0.f, 0.f, 0.f};
    z = __builtin_amdgcn_mfma_f32_16x16x32_bf16(aq0, bk0, z, 0, 0, 0);
    z = __builtin_amdgcn_mfma_f32_16x16x32_bf16(aq1, bk1, z, 0, 0, 0);
    sacc[cn] = z;
  }

  // row softmax: lane holds cols cn*16+lr of rows wq0 + lg*4 + jr
  #pragma unroll
  for (int jr = 0; jr < 4; ++jr){
    const int R = wq0 + lg*4 + jr;     // row within 64-block
    float v[8], mx = -1e30f;
    #pragma unroll
    for (int cn = 0; cn < 8; ++cn){
      int c = cn*16 + lr;
      float sc = sacc[cn][jr] * 0.125f + kb[c];
      if (c < R || c > R + 64) sc = -1e30f;   // band mask
      v[cn] = sc;
      mx = fmaxf(mx, sc);
    }
    #pragma unroll
    for (int o = 1; o < 16; o <<= 1) mx = fmaxf(mx, __shfl_xor(mx, o));
    float sum = 0.f;
    #pragma unroll
    for (int cn = 0; cn < 8; ++cn){ v[cn] = __expf(v[cn] - mx); sum += v[cn]; }
    #pragma unroll
    for (int o = 1; o < 16; o <<= 1) sum += __shfl_xor(sum, o);
    float qm = mask[rb + s0 + R];
    float inv = ((qm < 0.999f) ? 0.0f : 1.0f) / sum;
    #pragma unroll
    for (int cn = 0; cn < 8; ++cn)
      P_lds[R][cn*16 + lr] = f2b(v[cn] * inv);
  }
  // P write->read is within-wave (rows wq0..wq0+15); LDS ops are in-order per wave.

  // PV: ctx[16x64 strip] = P[16x128] @ V[128x64]
  short8v ap[4];
  #pragma unroll
  for (int ks = 0; ks < 4; ++ks)
    ap[ks] = *(const short8v*)(&P_lds[wq0 + lr][ks*32 + lk]);
  #pragma unroll
  for (int dn = 0; dn < 4; ++dn){
    f32x4 z = {0.f, 0.f, 0.f, 0.f};
    #pragma unroll
    for (int ks = 0; ks < 4; ++ks){
      short8v bv = *(const short8v*)(&Vt[dn*16 + lr][ks*32 + lk]);
      z = __builtin_amdgcn_mfma_f32_16x16x32_bf16(ap[ks], bv, z, 0, 0, 0);
    }
    #pragma unroll
    for (int jr = 0; jr < 4; ++jr){
      int R = wq0 + lg*4 + jr;
      ctx[(rb + s0 + R)*H_ + hh*64 + dn*16 + lr] = f2b(z[jr]);
    }
  }
}

// ---------------------------------------------------------------- pooling
__global__ __launch_bounds__(256) void pool_logit(const ushort* __restrict__ e,
    const float* __restrict__ w2, const float* __restrict__ b2p,
    const float* __restrict__ mask, float* __restrict__ alpha)
{
  int tid = threadIdx.x, wave = tid >> 6, lane = tid & 63;
  int r = blockIdx.x * 4 + wave;
  short8v ev = *(const short8v*)(e + (size_t)r*H_ + lane*8);
  float sacc = 0.f;
  #pragma unroll
  for (int j = 0; j < 8; ++j) sacc += b2f((ushort)ev[j]) * w2[lane*8 + j];
  #pragma unroll
  for (int o = 32; o > 0; o >>= 1) sacc += __shfl_xor(sacc, o);
  if (lane == 0){
    float logit = sacc + b2p[0];
    alpha[r] = __expf(logit) * mask[r];
  }
}

__global__ __launch_bounds__(256) void pool_sum(const float* __restrict__ alpha,
                                                float* __restrict__ invsum)
{
  __shared__ float red[4];
  int b = blockIdx.x, tid = threadIdx.x, wave = tid >> 6, lane = tid & 63;
  float s = 0.f;
  for (int k = tid; k < S_; k += 256) s += alpha[b*S_ + k];
  #pragma unroll
  for (int o = 32; o > 0; o >>= 1) s += __shfl_xor(s, o);
  if (lane == 0) red[wave] = s;
  __syncthreads();
  if (tid == 0) invsum[b] = 1.0f / (red[0] + red[1] + red[2] + red[3] + 1e-8f);
}

// deterministic chunked weighted sum: outacc[chunk][b][h]
__global__ __launch_bounds__(256) void pool_wsum(const float* __restrict__ x,
    const float* __restrict__ alpha, float* __restrict__ out_acc)
{
  int chunk = blockIdx.x, b = blockIdx.y, tid = threadIdx.x;
  int s0 = chunk * 128;
  float a0 = 0.f, a1 = 0.f;
  for (int i = 0; i < 128; ++i){
    int srow = s0 + i;
    float al = alpha[b*S_ + srow];
    a0 += x[(size_t)(b*S_ + srow)*H_ + tid]       * al;
    a1 += x[(size_t)(b*S_ + srow)*H_ + tid + 256] * al;
  }
  out_acc[(size_t)chunk*B_*H_ + b*H_ + tid]       = a0;
  out_acc[(size_t)chunk*B_*H_ + b*H_ + tid + 256] = a1;
}

__global__ __launch_bounds__(256) void pool_final(const float* __restrict__ out_acc,
    const float* __restrict__ invsum, float* __restrict__ out)
{
  int i = blockIdx.x * 256 + threadIdx.x;
  if (i < B_*H_){
    int b = i >> 9;
    float s = 0.f;
    #pragma unroll
    for (int c = 0; c < 16; ++c) s += out_acc[(size_t)c*B_*H_ + i];
    out[i] = s * invsum[b];
  }
}

// ---------------------------------------------------------------- launch
extern "C" void kernel_launch(void* const* d_in, const int* in_sizes, int n_in,
                              void* d_out, int out_size, void* d_ws, size_t ws_size,
                              hipStream_t stream)
{
  const float* input_embs = (const float*)d_in[0];
  const float* mask       = (const float*)d_in[1];
  const float* pos        = (const float*)d_in[2];
  const float* ln_emb_g   = (const float*)d_in[3];
  const float* ln_emb_b   = (const float*)d_in[4];
  const float* Wq  = (const float*)d_in[5];
  const float* bq  = (const float*)d_in[6];
  const float* Wk  = (const float*)d_in[7];
  const float* bk  = (const float*)d_in[8];
  const float* Wv  = (const float*)d_in[9];
  const float* bv  = (const float*)d_in[10];
  const float* Wo  = (const float*)d_in[11];
  const float* bo  = (const float*)d_in[12];
  const float* ln1_g = (const float*)d_in[13];
  const float* ln1_b = (const float*)d_in[14];
  const float* Wi  = (const float*)d_in[15];
  const float* bi  = (const float*)d_in[16];
  const float* Wo2 = (const float*)d_in[17];
  const float* bo2 = (const float*)d_in[18];
  const float* ln2_g = (const float*)d_in[19];
  const float* ln2_b = (const float*)d_in[20];
  const float* pW1 = (const float*)d_in[21];
  const float* pb1 = (const float*)d_in[22];
  const float* pW2 = (const float*)d_in[23];
  const float* pb2 = (const float*)d_in[24];

  char* ws = (char*)d_ws;
  size_t off = 0;
  auto alloc = [&](size_t bytes)->char*{
    char* p = ws + off; off += (bytes + 255) & ~(size_t)255; return p;
  };
  ushort* WqkvT  = (ushort*)alloc((size_t)L_*1536*512*2);
  ushort* WoT    = (ushort*)alloc((size_t)L_*512*512*2);
  ushort* WiT    = (ushort*)alloc((size_t)L_*2048*512*2);
  ushort* Wo2T   = (ushort*)alloc((size_t)L_*512*2048*2);
  ushort* pW1T   = (ushort*)alloc((size_t)512*512*2);
  float*  bqkv   = (float*)alloc((size_t)L_*1536*4);
  ushort* h16    = (ushort*)alloc((size_t)M_*H_*2);
  float*  h32    = (float*)alloc((size_t)M_*H_*4);
  ushort* qkv    = (ushort*)alloc((size_t)M_*1536*2);
  ushort* ctx    = (ushort*)alloc((size_t)M_*H_*2);
  ushort* attn16 = (ushort*)alloc((size_t)M_*H_*2);
  float*  attn32 = (float*)alloc((size_t)M_*H_*4);
  ushort* inter  = (ushort*)alloc((size_t)M_*INTER_*2);
  float*  t1     = (float*)alloc((size_t)2*M_*H_*4);   // 2 split-K partials
  float*  alpha  = (float*)alloc((size_t)M_*4);
  float*  invsum = (float*)alloc(256);
  float*  outacc = (float*)alloc((size_t)16*B_*H_*4);

  dim3 tb(256);
  transpose_k<<<dim3(16,16,L_), tb, 0, stream>>>(Wq, WqkvT,            512,  512, (size_t)512*512,  (size_t)1536*512);
  transpose_k<<<dim3(16,16,L_), tb, 0, stream>>>(Wk, WqkvT + 512*512,  512,  512, (size_t)512*512,  (size_t)1536*512);
  transpose_k<<<dim3(16,16,L_), tb, 0, stream>>>(Wv, WqkvT + 1024*512, 512,  512, (size_t)512*512,  (size_t)1536*512);
  transpose_k<<<dim3(16,16,L_), tb, 0, stream>>>(Wo, WoT,              512,  512, (size_t)512*512,  (size_t)512*512);
  transpose_k<<<dim3(64,16,L_), tb, 0, stream>>>(Wi, WiT,              512, 2048, (size_t)512*2048, (size_t)2048*512);
  transpose_k<<<dim3(16,64,L_), tb, 0, stream>>>(Wo2, Wo2T,           2048,  512, (size_t)2048*512, (size_t)512*2048);
  transpose_k<<<dim3(16,16,1),  tb, 0, stream>>>(pW1, pW1T,            512,  512, 0, 0);
  pack_bqkv<<<dim3(L_*1536/256), tb, 0, stream>>>(bq, bk, bv, bqkv);

  embed_ln<<<dim3(M_), tb, 0, stream>>>(input_embs, pos, ln_emb_g, ln_emb_b, h16, h32);

  for (int l = 0; l < L_; ++l){
    gemm_bt<0><<<dim3(12,32,1), tb, 0, stream>>>(h16, WqkvT + (size_t)l*1536*512, bqkv + l*1536,
                                                 qkv, nullptr, M_, 1536, 512, 512);
    attn_mfma<<<dim3(S_/64, B_*NH_), tb, 0, stream>>>(qkv, mask, ctx);
    gemm_wo_ln<<<dim3(M_/16), tb, 0, stream>>>(ctx, WoT + (size_t)l*512*512, bo + l*512,
                                               h32, ln1_g + l*512, ln1_b + l*512, attn16, attn32);
    gemm_bt<1><<<dim3(16,32,1), tb, 0, stream>>>(attn16, WiT + (size_t)l*2048*512, bi + l*2048,
                                                 inter, nullptr, M_, 2048, 512, 512);
    gemm_bt<3><<<dim3(4,32,2), tb, 0, stream>>>(inter, Wo2T + (size_t)l*512*2048, bo2 + l*512,
                                                nullptr, t1, M_, 512, 2048, 1024);
    ln_res<<<dim3(M_), tb, 0, stream>>>(t1, attn32, ln2_g + l*512, ln2_b + l*512, h16, h32);
  }

  // pooling: e = tanh(h @ pW1 + pb1)  (reuse ctx buffer for e)
  gemm_bt<2><<<dim3(4,32,1), tb, 0, stream>>>(h16, pW1T, pb1, ctx, nullptr, M_, 512, 512, 512);
  pool_logit<<<dim3(M_/4), tb, 0, stream>>>(ctx, pW2, pb2, mask, alpha);
  pool_sum<<<dim3(B_), tb, 0, stream>>>(alpha, invsum);
  pool_wsum<<<dim3(16, B_), tb, 0, stream>>>(h32, alpha, outacc);
  pool_final<<<dim3((B_*H_ + 255)/256), tb, 0, stream>>>(outacc, invsum, (float*)d_out);
}

// Round 7
// 448.371 us; speedup vs baseline: 1.0599x; 1.0599x over previous
//
#include <hip/hip_runtime.h>
#include <hip/hip_bf16.h>
#include <math.h>

#define B_ 2
#define S_ 2048
#define H_ 512
#define NH_ 8
#define HD_ 64
#define L_ 4
#define INTER_ 2048
#define W1_ 32
#define WB_ 65
#define M_ (B_*S_)   // 4096

typedef __attribute__((ext_vector_type(8))) short short8v;
typedef __attribute__((ext_vector_type(4))) float f32x4;

__device__ __forceinline__ float b2f(ushort u){ return __uint_as_float(((unsigned)u)<<16); }
__device__ __forceinline__ ushort f2b(float f){
  unsigned u = __float_as_uint(f);
  unsigned r = (u + 0x7fffu + ((u>>16)&1u)) >> 16;
  return (ushort)r;
}

// async global->LDS, 16B per lane (linear LDS dest = base + lane*16).
__device__ __forceinline__ void async16(const ushort* g, ushort* l){
  __builtin_amdgcn_global_load_lds(
      (const __attribute__((address_space(1))) unsigned int*)g,
      (__attribute__((address_space(3))) unsigned int*)l, 16, 0, 0);
}

// ---------------------------------------------------------------- transpose+cvt
// src [R][C] f32 row-major -> dst [C][R] bf16 row-major (batched over z)
__global__ __launch_bounds__(256) void transpose_k(const float* __restrict__ src,
    ushort* __restrict__ dst, int R, int C, size_t sBatch, size_t dBatch)
{
  __shared__ ushort tile[32][33];
  src += (size_t)blockIdx.z * sBatch;
  dst += (size_t)blockIdx.z * dBatch;
  int tx = threadIdx.x & 31, ty = threadIdx.x >> 5;   // 32 x 8
  int r0 = blockIdx.y * 32, c0 = blockIdx.x * 32;
  #pragma unroll
  for (int i = 0; i < 4; ++i){
    int r = r0 + ty + i*8;
    tile[ty + i*8][tx] = f2b(src[(size_t)r * C + c0 + tx]);
  }
  __syncthreads();
  #pragma unroll
  for (int i = 0; i < 4; ++i){
    int c = c0 + ty + i*8;
    dst[(size_t)c * R + r0 + tx] = tile[tx][ty + i*8];
  }
}

__global__ __launch_bounds__(256) void pack_bqkv(const float* __restrict__ bq,
    const float* __restrict__ bk, const float* __restrict__ bv, float* __restrict__ dst)
{
  int i = blockIdx.x * 256 + threadIdx.x;      // < L_*1536
  int l = i / 1536, n = i % 1536;
  float v = (n < 512) ? bq[l*512 + n] : (n < 1024 ? bk[l*512 + n - 512] : bv[l*512 + n - 1024]);
  dst[i] = v;
}

// ---------------------------------------------------------------- GEMM (B^T)
// C[M,N] = A[M,K(part)] @ Bt[N,K]^T (+ bias on z==0)
// EPI: 0=bf16, 1=gelu->bf16, 2=tanh->bf16, 3=f32 (split-K partial at z*M*N)
// BM=64, BN=128, BK=32; 4 waves; double-buffered global_load_lds prefetch.
template<int EPI>
__global__ __launch_bounds__(256, 4) void gemm_bt(
    const ushort* __restrict__ A, const ushort* __restrict__ Bt,
    const float* __restrict__ bias, ushort* __restrict__ o16,
    float* __restrict__ o32, int M, int N, int K, int Klen)
{
  __shared__ ushort lds_a[2][64][32];    // 8 KB
  __shared__ ushort lds_b[2][128][32];   // 16 KB
  const int tid = threadIdx.x;
  const int bm = blockIdx.y * 64, bn = blockIdx.x * 128;
  const int kbeg = blockIdx.z * Klen;
  const int wave = tid >> 6, lane = tid & 63;
  const int wr = (wave >> 1) * 32, wc = (wave & 1) * 64;
  const int lr = lane & 15, lg = lane >> 4, lk = lg * 8;
  f32x4 acc[2][4] = {};

  // staging map: thread t -> row t>>2, 16B chunk t&3 (linear LDS == tid*16 B)
  const int srow = tid >> 2, schk = (tid & 3) * 8;
  const ushort* Ag  = A  + (size_t)(bm + srow) * K + kbeg + schk;
  const ushort* Bg0 = Bt + (size_t)(bn + srow) * K + kbeg + schk;
  const ushort* Bg1 = Bt + (size_t)(bn + 64 + srow) * K + kbeg + schk;
  ushort* la = &lds_a[0][0][0] + tid * 8;      // +2048 per buffer
  ushort* lb = &lds_b[0][0][0] + tid * 8;      // +4096 per buffer, +2048 second half

  const int nIter = Klen >> 5;
  // prologue: stage tile 0 into buf 0
  async16(Ag, la);
  async16(Bg0, lb);
  async16(Bg1, lb + 2048);
  __syncthreads();

  int cur = 0;
  for (int t = 0; t < nIter; ++t){
    if (t + 1 < nIter){                  // prefetch next tile into buf cur^1
      int k0 = (t + 1) << 5;
      int nb = cur ^ 1;
      async16(Ag  + k0, la + nb*2048);
      async16(Bg0 + k0, lb + nb*4096);
      async16(Bg1 + k0, lb + nb*4096 + 2048);
    }
    short8v af[2], bfr[4];
    #pragma unroll
    for (int mi = 0; mi < 2; ++mi)
      af[mi] = *(const short8v*)(&lds_a[cur][wr + mi*16 + lr][lk]);
    #pragma unroll
    for (int nj = 0; nj < 4; ++nj)
      bfr[nj] = *(const short8v*)(&lds_b[cur][wc + nj*16 + lr][lk]);
    #pragma unroll
    for (int mi = 0; mi < 2; ++mi)
      #pragma unroll
      for (int nj = 0; nj < 4; ++nj)
        acc[mi][nj] = __builtin_amdgcn_mfma_f32_16x16x32_bf16(af[mi], bfr[nj], acc[mi][nj], 0, 0, 0);
    __syncthreads();                     // drains prefetch vmcnt + guards reuse
    cur ^= 1;
  }

  const float bscale = (blockIdx.z == 0) ? 1.0f : 0.0f;
  #pragma unroll
  for (int mi = 0; mi < 2; ++mi){
    #pragma unroll
    for (int nj = 0; nj < 4; ++nj){
      int col = bn + wc + nj*16 + lr;
      float bv = bias[col] * bscale;
      #pragma unroll
      for (int j = 0; j < 4; ++j){
        int row = bm + wr + mi*16 + lg*4 + j;
        float v = acc[mi][nj][j] + bv;
        if (EPI == 1) v = 0.5f * v * (1.0f + erff(v * 0.70710678118654752f));
        if (EPI == 2) v = tanhf(v);
        if (EPI == 3) o32[(size_t)blockIdx.z*M*N + (size_t)row * N + col] = v;
        else          o16[(size_t)row * N + col] = f2b(v);
      }
    }
  }
}

// ---------------------------------------------------------------- fused Wo GEMM + residual + LN
// out = LN(A @ Bt^T + bias + res).  BM=16, BN=512 (full row), K=512.
// 4 waves; wave w covers cols w*128; grid = M/16 = 256 blocks.
__global__ __launch_bounds__(256) void gemm_wo_ln(
    const ushort* __restrict__ A, const ushort* __restrict__ Bt,
    const float* __restrict__ bias, const float* __restrict__ res,
    const float* __restrict__ g, const float* __restrict__ bb,
    ushort* __restrict__ out16, float* __restrict__ out32)
{
  __shared__ ushort lds_a[2][16][32];    // 2 KB
  __shared__ ushort lds_b[2][512][32];   // 64 KB
  __shared__ float  red[4][2][16];

  const int tid = threadIdx.x;
  const int bm = blockIdx.x * 16;
  const int wave = tid >> 6, lane = tid & 63;
  const int wc = wave * 128;
  const int lr = lane & 15, lg = lane >> 4, lk = lg * 8;
  f32x4 acc[8] = {};

  const ushort* Ag = A  + (size_t)(bm + (tid >> 2)) * 512 + (tid & 3) * 8;   // tid<64 only
  const ushort* Bg = Bt + (size_t)(tid >> 2) * 512 + (tid & 3) * 8;          // +r*64 rows
  ushort* la = &lds_a[0][0][0] + tid * 8;     // buffer stride 512
  ushort* lb = &lds_b[0][0][0] + tid * 8;     // buffer stride 16384, round stride 2048

  // prologue: stage tile 0
  if (tid < 64) async16(Ag, la);
  #pragma unroll
  for (int r = 0; r < 8; ++r) async16(Bg + (size_t)r*64*512, lb + r*2048);
  __syncthreads();

  int cur = 0;
  for (int t = 0; t < 16; ++t){
    if (t < 15){
      int k0 = (t + 1) * 32;
      int nb = cur ^ 1;
      if (tid < 64) async16(Ag + k0, la + nb*512);
      #pragma unroll
      for (int r = 0; r < 8; ++r)
        async16(Bg + (size_t)r*64*512 + k0, lb + nb*16384 + r*2048);
    }
    short8v af = *(const short8v*)(&lds_a[cur][lr][lk]);
    #pragma unroll
    for (int nj = 0; nj < 8; ++nj){
      short8v bf = *(const short8v*)(&lds_b[cur][wc + nj*16 + lr][lk]);
      acc[nj] = __builtin_amdgcn_mfma_f32_16x16x32_bf16(af, bf, acc[nj], 0, 0, 0);
    }
    __syncthreads();
    cur ^= 1;
  }

  // epilogue: v = acc + bias + res; LN over full 512-wide rows
  float vv[8][4];
  float sm[4] = {0,0,0,0}, sq[4] = {0,0,0,0};
  #pragma unroll
  for (int nj = 0; nj < 8; ++nj){
    int col = wc + nj*16 + lr;
    float bv = bias[col];
    #pragma unroll
    for (int j = 0; j < 4; ++j){
      int grow = bm + lg*4 + j;
      float v = acc[nj][j] + bv + res[(size_t)grow*512 + col];
      vv[nj][j] = v;
      sm[j] += v;
      sq[j] += v*v;
    }
  }
  #pragma unroll
  for (int o = 1; o < 16; o <<= 1){
    #pragma unroll
    for (int j = 0; j < 4; ++j){
      sm[j] += __shfl_xor(sm[j], o);
      sq[j] += __shfl_xor(sq[j], o);
    }
  }
  if (lr == 0){
    #pragma unroll
    for (int j = 0; j < 4; ++j){
      red[wave][0][lg*4 + j] = sm[j];
      red[wave][1][lg*4 + j] = sq[j];
    }
  }
  __syncthreads();
  float mean[4], rstd[4];
  #pragma unroll
  for (int j = 0; j < 4; ++j){
    int R = lg*4 + j;
    float S = red[0][0][R] + red[1][0][R] + red[2][0][R] + red[3][0][R];
    float Q = red[0][1][R] + red[1][1][R] + red[2][1][R] + red[3][1][R];
    mean[j] = S * (1.0f / 512.0f);
    float var = Q * (1.0f / 512.0f) - mean[j]*mean[j];
    if (var < 0.f) var = 0.f;
    rstd[j] = rsqrtf(var + 1e-12f);
  }
  #pragma unroll
  for (int nj = 0; nj < 8; ++nj){
    int col = wc + nj*16 + lr;
    float gv = g[col], bbv = bb[col];
    #pragma unroll
    for (int j = 0; j < 4; ++j){
      int grow = bm + lg*4 + j;
      float o = (vv[nj][j] - mean[j]) * rstd[j] * gv + bbv;
      out16[(size_t)grow*512 + col] = f2b(o);
      out32[(size_t)grow*512 + col] = o;
    }
  }
}

// ---------------------------------------------------------------- LayerNorm
__device__ __forceinline__ void block_ln_stats(float v0, float v1, float* red,
                                               float& mean, float& rstd)
{
  int tid = threadIdx.x, wave = tid >> 6, lane = tid & 63;
  float sm = v0 + v1;
  float sq = v0*v0 + v1*v1;
  #pragma unroll
  for (int o = 32; o > 0; o >>= 1){ sm += __shfl_xor(sm, o); sq += __shfl_xor(sq, o); }
  if (lane == 0){ red[wave] = sm; red[4 + wave] = sq; }
  __syncthreads();
  float S = red[0] + red[1] + red[2] + red[3];
  float Q = red[4] + red[5] + red[6] + red[7];
  mean = S * (1.0f / 512.0f);
  float var = Q * (1.0f / 512.0f) - mean*mean;
  if (var < 0.f) var = 0.f;
  rstd = rsqrtf(var + 1e-12f);
}

// embeddings LN (float2 vectorized): x,pos f32 -> out bf16 + f32 shadow
__global__ __launch_bounds__(256) void embed_ln(const float* __restrict__ x,
    const float* __restrict__ pos, const float* __restrict__ g,
    const float* __restrict__ bb, ushort* __restrict__ out16, float* __restrict__ out32)
{
  __shared__ float red[8];
  int row = blockIdx.x, tid = threadIdx.x;
  int s = row & (S_ - 1);
  const size_t base = (size_t)row*H_ + tid*2;
  float2 xv = *(const float2*)(x + base);
  float2 pv = *(const float2*)(pos + (size_t)s*H_ + tid*2);
  float v0 = xv.x + pv.x, v1 = xv.y + pv.y;
  float mean, rstd;
  block_ln_stats(v0, v1, red, mean, rstd);
  float2 gv = *(const float2*)(g + tid*2);
  float2 bv = *(const float2*)(bb + tid*2);
  float r0 = (v0 - mean)*rstd*gv.x + bv.x;
  float r1 = (v1 - mean)*rstd*gv.y + bv.y;
  ushort2 o2; o2.x = f2b(r0); o2.y = f2b(r1);
  *(ushort2*)(out16 + base) = o2;
  float2 f2v; f2v.x = r0; f2v.y = r1;
  *(float2*)(out32 + base) = f2v;
}

// LN(t0 + t1 + res32) float2 vectorized
__global__ __launch_bounds__(256) void ln_res(const float* __restrict__ t,
    const float* __restrict__ res, const float* __restrict__ g,
    const float* __restrict__ bb, ushort* __restrict__ out16, float* __restrict__ out32)
{
  __shared__ float red[8];
  int row = blockIdx.x, tid = threadIdx.x;
  const size_t MN = (size_t)M_*H_;
  const size_t base = (size_t)row*H_ + tid*2;
  float2 t0 = *(const float2*)(t + base);
  float2 t1v = *(const float2*)(t + MN + base);
  float2 rv = *(const float2*)(res + base);
  float v0 = t0.x + t1v.x + rv.x;
  float v1 = t0.y + t1v.y + rv.y;
  float mean, rstd;
  block_ln_stats(v0, v1, red, mean, rstd);
  float2 gv = *(const float2*)(g + tid*2);
  float2 bv = *(const float2*)(bb + tid*2);
  float r0 = (v0 - mean)*rstd*gv.x + bv.x;
  float r1 = (v1 - mean)*rstd*gv.y + bv.y;
  ushort2 o2; o2.x = f2b(r0); o2.y = f2b(r1);
  *(ushort2*)(out16 + base) = o2;
  float2 f2v; f2v.x = r0; f2v.y = r1;
  *(float2*)(out32 + base) = f2v;
}

// ---------------------------------------------------------------- attention (MFMA)
// qkv: [B*S][1536] bf16 (q|k|v each 512). Block: 256 thr (4 waves) = one
// (b,h) x 64-row Q-block. Keys/values: 128-wide chunk [s0-32, s0+95].
__global__ __launch_bounds__(256) void attn_mfma(const ushort* __restrict__ qkv,
    const float* __restrict__ mask, ushort* __restrict__ ctx)
{
  __shared__ ushort K_lds[128][72];   // [key c][k]   (pad 72: 2-way free)
  __shared__ ushort Vt[64][136];      // [d][key c]   (pad 136)
  __shared__ ushort P_lds[64][136];   // [q row][key c]
  __shared__ float  kb[128];

  const int tid = threadIdx.x, wave = tid >> 6, lane = tid & 63;
  const int hh = blockIdx.y & (NH_ - 1), b = blockIdx.y >> 3;
  const int s0 = blockIdx.x * 64;
  const size_t rb = (size_t)b * S_;

  // ---- stage K rows c=0..127 and V^T
  const int ch = tid & 7;             // 16B chunk within 64-d row
  const int rr = tid >> 3;            // 0..31
  #pragma unroll
  for (int it = 0; it < 4; ++it){
    int c = rr + it*32;
    int j = s0 - 32 + c;
    int jc = min(max(j, 0), S_ - 1);
    const size_t rowb = (rb + jc) * 1536 + hh*64 + ch*8;
    *(short8v*)(&K_lds[c][ch*8]) = *(const short8v*)(qkv + rowb + 512);
    short8v vv = *(const short8v*)(qkv + rowb + 1024);
    #pragma unroll
    for (int t = 0; t < 8; ++t){      // staggered transpose write (<=2-way)
      int tt = (t + ch) & 7;
      Vt[ch*8 + tt][c] = (ushort)vv[tt];
    }
  }
  if (tid < 128){
    int j = s0 - 32 + tid;
    kb[tid] = (j >= 0 && j < S_) ? (1.0f - mask[rb + j]) * (-10000.0f) : -1e30f;
  }
  __syncthreads();

  const int wq0 = wave * 16;
  const int lr = lane & 15, lg = lane >> 4, lk = lg * 8;

  // Q fragments (A): row = wq0+lr, k = lk..lk+7 (+32 for second frag)
  const ushort* qbase = qkv + (rb + s0 + wq0 + lr) * 1536 + hh*64;
  short8v aq0 = *(const short8v*)(qbase + lk);
  short8v aq1 = *(const short8v*)(qbase + 32 + lk);

  // scores: 16x128 strip per wave
  f32x4 sacc[8];
  #pragma unroll
  for (int cn = 0; cn < 8; ++cn){
    short8v bk0 = *(const short8v*)(&K_lds[cn*16 + lr][lk]);
    short8v bk1 = *(const short8v*)(&K_lds[cn*16 + lr][32 + lk]);
    f32x4 z = {0.f, 0.f, 0.f, 0.f};
    z = __builtin_amdgcn_mfma_f32_16x16x32_bf16(aq0, bk0, z, 0, 0, 0);
    z = __builtin_amdgcn_mfma_f32_16x16x32_bf16(aq1, bk1, z, 0, 0, 0);
    sacc[cn] = z;
  }

  // row softmax: lane holds cols cn*16+lr of rows wq0 + lg*4 + jr
  #pragma unroll
  for (int jr = 0; jr < 4; ++jr){
    const int R = wq0 + lg*4 + jr;     // row within 64-block
    float v[8], mx = -1e30f;
    #pragma unroll
    for (int cn = 0; cn < 8; ++cn){
      int c = cn*16 + lr;
      float sc = sacc[cn][jr] * 0.125f + kb[c];
      if (c < R || c > R + 64) sc = -1e30f;   // band mask
      v[cn] = sc;
      mx = fmaxf(mx, sc);
    }
    #pragma unroll
    for (int o = 1; o < 16; o <<= 1) mx = fmaxf(mx, __shfl_xor(mx, o));
    float sum = 0.f;
    #pragma unroll
    for (int cn = 0; cn < 8; ++cn){ v[cn] = __expf(v[cn] - mx); sum += v[cn]; }
    #pragma unroll
    for (int o = 1; o < 16; o <<= 1) sum += __shfl_xor(sum, o);
    float qm = mask[rb + s0 + R];
    float inv = ((qm < 0.999f) ? 0.0f : 1.0f) / sum;
    #pragma unroll
    for (int cn = 0; cn < 8; ++cn)
      P_lds[R][cn*16 + lr] = f2b(v[cn] * inv);
  }
  // P write->read is within-wave (rows wq0..wq0+15); LDS ops are in-order per wave.

  // PV: ctx[16x64 strip] = P[16x128] @ V[128x64]
  short8v ap[4];
  #pragma unroll
  for (int ks = 0; ks < 4; ++ks)
    ap[ks] = *(const short8v*)(&P_lds[wq0 + lr][ks*32 + lk]);
  #pragma unroll
  for (int dn = 0; dn < 4; ++dn){
    f32x4 z = {0.f, 0.f, 0.f, 0.f};
    #pragma unroll
    for (int ks = 0; ks < 4; ++ks){
      short8v bv = *(const short8v*)(&Vt[dn*16 + lr][ks*32 + lk]);
      z = __builtin_amdgcn_mfma_f32_16x16x32_bf16(ap[ks], bv, z, 0, 0, 0);
    }
    #pragma unroll
    for (int jr = 0; jr < 4; ++jr){
      int R = wq0 + lg*4 + jr;
      ctx[(rb + s0 + R)*H_ + hh*64 + dn*16 + lr] = f2b(z[jr]);
    }
  }
}

// ---------------------------------------------------------------- pooling
__global__ __launch_bounds__(256) void pool_logit(const ushort* __restrict__ e,
    const float* __restrict__ w2, const float* __restrict__ b2p,
    const float* __restrict__ mask, float* __restrict__ alpha)
{
  int tid = threadIdx.x, wave = tid >> 6, lane = tid & 63;
  int r = blockIdx.x * 4 + wave;
  short8v ev = *(const short8v*)(e + (size_t)r*H_ + lane*8);
  float sacc = 0.f;
  #pragma unroll
  for (int j = 0; j < 8; ++j) sacc += b2f((ushort)ev[j]) * w2[lane*8 + j];
  #pragma unroll
  for (int o = 32; o > 0; o >>= 1) sacc += __shfl_xor(sacc, o);
  if (lane == 0){
    float logit = sacc + b2p[0];
    alpha[r] = __expf(logit) * mask[r];
  }
}

__global__ __launch_bounds__(256) void pool_sum(const float* __restrict__ alpha,
                                                float* __restrict__ invsum)
{
  __shared__ float red[4];
  int b = blockIdx.x, tid = threadIdx.x, wave = tid >> 6, lane = tid & 63;
  float s = 0.f;
  for (int k = tid; k < S_; k += 256) s += alpha[b*S_ + k];
  #pragma unroll
  for (int o = 32; o > 0; o >>= 1) s += __shfl_xor(s, o);
  if (lane == 0) red[wave] = s;
  __syncthreads();
  if (tid == 0) invsum[b] = 1.0f / (red[0] + red[1] + red[2] + red[3] + 1e-8f);
}

// deterministic chunked weighted sum (float2): outacc[chunk][b][h]
__global__ __launch_bounds__(256) void pool_wsum(const float* __restrict__ x,
    const float* __restrict__ alpha, float* __restrict__ out_acc)
{
  int chunk = blockIdx.x, b = blockIdx.y, tid = threadIdx.x;
  int s0 = chunk * 128;
  int c0 = tid * 2;
  float a0 = 0.f, a1 = 0.f;
  for (int i = 0; i < 128; ++i){
    int srow = s0 + i;
    float al = alpha[b*S_ + srow];
    float2 xv = *(const float2*)(x + (size_t)(b*S_ + srow)*H_ + c0);
    a0 += xv.x * al;
    a1 += xv.y * al;
  }
  float2 o; o.x = a0; o.y = a1;
  *(float2*)(out_acc + (size_t)chunk*B_*H_ + b*H_ + c0) = o;
}

__global__ __launch_bounds__(256) void pool_final(const float* __restrict__ out_acc,
    const float* __restrict__ invsum, float* __restrict__ out)
{
  int i = blockIdx.x * 256 + threadIdx.x;
  if (i < B_*H_){
    int b = i >> 9;
    float s = 0.f;
    #pragma unroll
    for (int c = 0; c < 16; ++c) s += out_acc[(size_t)c*B_*H_ + i];
    out[i] = s * invsum[b];
  }
}

// ---------------------------------------------------------------- launch
extern "C" void kernel_launch(void* const* d_in, const int* in_sizes, int n_in,
                              void* d_out, int out_size, void* d_ws, size_t ws_size,
                              hipStream_t stream)
{
  const float* input_embs = (const float*)d_in[0];
  const float* mask       = (const float*)d_in[1];
  const float* pos        = (const float*)d_in[2];
  const float* ln_emb_g   = (const float*)d_in[3];
  const float* ln_emb_b   = (const float*)d_in[4];
  const float* Wq  = (const float*)d_in[5];
  const float* bq  = (const float*)d_in[6];
  const float* Wk  = (const float*)d_in[7];
  const float* bk  = (const float*)d_in[8];
  const float* Wv  = (const float*)d_in[9];
  const float* bv  = (const float*)d_in[10];
  const float* Wo  = (const float*)d_in[11];
  const float* bo  = (const float*)d_in[12];
  const float* ln1_g = (const float*)d_in[13];
  const float* ln1_b = (const float*)d_in[14];
  const float* Wi  = (const float*)d_in[15];
  const float* bi  = (const float*)d_in[16];
  const float* Wo2 = (const float*)d_in[17];
  const float* bo2 = (const float*)d_in[18];
  const float* ln2_g = (const float*)d_in[19];
  const float* ln2_b = (const float*)d_in[20];
  const float* pW1 = (const float*)d_in[21];
  const float* pb1 = (const float*)d_in[22];
  const float* pW2 = (const float*)d_in[23];
  const float* pb2 = (const float*)d_in[24];

  char* ws = (char*)d_ws;
  size_t off = 0;
  auto alloc = [&](size_t bytes)->char*{
    char* p = ws + off; off += (bytes + 255) & ~(size_t)255; return p;
  };
  ushort* WqkvT  = (ushort*)alloc((size_t)L_*1536*512*2);
  ushort* WoT    = (ushort*)alloc((size_t)L_*512*512*2);
  ushort* WiT    = (ushort*)alloc((size_t)L_*2048*512*2);
  ushort* Wo2T   = (ushort*)alloc((size_t)L_*512*2048*2);
  ushort* pW1T   = (ushort*)alloc((size_t)512*512*2);
  float*  bqkv   = (float*)alloc((size_t)L_*1536*4);
  ushort* h16    = (ushort*)alloc((size_t)M_*H_*2);
  float*  h32    = (float*)alloc((size_t)M_*H_*4);
  ushort* qkv    = (ushort*)alloc((size_t)M_*1536*2);
  ushort* ctx    = (ushort*)alloc((size_t)M_*H_*2);
  ushort* attn16 = (ushort*)alloc((size_t)M_*H_*2);
  float*  attn32 = (float*)alloc((size_t)M_*H_*4);
  ushort* inter  = (ushort*)alloc((size_t)M_*INTER_*2);
  float*  t1     = (float*)alloc((size_t)2*M_*H_*4);   // 2 split-K partials
  float*  alpha  = (float*)alloc((size_t)M_*4);
  float*  invsum = (float*)alloc(256);
  float*  outacc = (float*)alloc((size_t)16*B_*H_*4);

  dim3 tb(256);
  transpose_k<<<dim3(16,16,L_), tb, 0, stream>>>(Wq, WqkvT,            512,  512, (size_t)512*512,  (size_t)1536*512);
  transpose_k<<<dim3(16,16,L_), tb, 0, stream>>>(Wk, WqkvT + 512*512,  512,  512, (size_t)512*512,  (size_t)1536*512);
  transpose_k<<<dim3(16,16,L_), tb, 0, stream>>>(Wv, WqkvT + 1024*512, 512,  512, (size_t)512*512,  (size_t)1536*512);
  transpose_k<<<dim3(16,16,L_), tb, 0, stream>>>(Wo, WoT,              512,  512, (size_t)512*512,  (size_t)512*512);
  transpose_k<<<dim3(64,16,L_), tb, 0, stream>>>(Wi, WiT,              512, 2048, (size_t)512*2048, (size_t)2048*512);
  transpose_k<<<dim3(16,64,L_), tb, 0, stream>>>(Wo2, Wo2T,           2048,  512, (size_t)2048*512, (size_t)512*2048);
  transpose_k<<<dim3(16,16,1),  tb, 0, stream>>>(pW1, pW1T,            512,  512, 0, 0);
  pack_bqkv<<<dim3(L_*1536/256), tb, 0, stream>>>(bq, bk, bv, bqkv);

  embed_ln<<<dim3(M_), tb, 0, stream>>>(input_embs, pos, ln_emb_g, ln_emb_b, h16, h32);

  for (int l = 0; l < L_; ++l){
    gemm_bt<0><<<dim3(12,64,1), tb, 0, stream>>>(h16, WqkvT + (size_t)l*1536*512, bqkv + l*1536,
                                                 qkv, nullptr, M_, 1536, 512, 512);
    attn_mfma<<<dim3(S_/64, B_*NH_), tb, 0, stream>>>(qkv, mask, ctx);
    gemm_wo_ln<<<dim3(M_/16), tb, 0, stream>>>(ctx, WoT + (size_t)l*512*512, bo + l*512,
                                               h32, ln1_g + l*512, ln1_b + l*512, attn16, attn32);
    gemm_bt<1><<<dim3(16,64,1), tb, 0, stream>>>(attn16, WiT + (size_t)l*2048*512, bi + l*2048,
                                                 inter, nullptr, M_, 2048, 512, 512);
    gemm_bt<3><<<dim3(4,64,2), tb, 0, stream>>>(inter, Wo2T + (size_t)l*512*2048, bo2 + l*512,
                                                nullptr, t1, M_, 512, 2048, 1024);
    ln_res<<<dim3(M_), tb, 0, stream>>>(t1, attn32, ln2_g + l*512, ln2_b + l*512, h16, h32);
  }

  // pooling: e = tanh(h @ pW1 + pb1)  (reuse ctx buffer for e)
  gemm_bt<2><<<dim3(4,64,1), tb, 0, stream>>>(h16, pW1T, pb1, ctx, nullptr, M_, 512, 512, 512);
  pool_logit<<<dim3(M_/4), tb, 0, stream>>>(ctx, pW2, pb2, mask, alpha);
  pool_sum<<<dim3(B_), tb, 0, stream>>>(alpha, invsum);
  pool_wsum<<<dim3(16, B_), tb, 0, stream>>>(h32, alpha, outacc);
  pool_final<<<dim3((B_*H_ + 255)/256), tb, 0, stream>>>(outacc, invsum, (float*)d_out);
}

// Round 8
// 415.759 us; speedup vs baseline: 1.1431x; 1.0784x over previous
//
#include <hip/hip_runtime.h>
#include <hip/hip_bf16.h>
#include <math.h>

#define B_ 2
#define S_ 2048
#define H_ 512
#define NH_ 8
#define HD_ 64
#define L_ 4
#define INTER_ 2048
#define W1_ 32
#define WB_ 65
#define M_ (B_*S_)   // 4096

typedef __attribute__((ext_vector_type(8))) short short8v;
typedef __attribute__((ext_vector_type(4))) float f32x4;

__device__ __forceinline__ float b2f(ushort u){ return __uint_as_float(((unsigned)u)<<16); }
__device__ __forceinline__ ushort f2b(float f){
  unsigned u = __float_as_uint(f);
  unsigned r = (u + 0x7fffu + ((u>>16)&1u)) >> 16;
  return (ushort)r;
}

// async global->LDS, 16B per lane (linear LDS dest = base + lane*16).
__device__ __forceinline__ void async16(const ushort* g, ushort* l){
  __builtin_amdgcn_global_load_lds(
      (const __attribute__((address_space(1))) unsigned int*)g,
      (__attribute__((address_space(3))) unsigned int*)l, 16, 0, 0);
}

// ---------------------------------------------------------------- transpose+cvt
// src [R][C] f32 row-major -> dst [C][R] bf16 row-major (batched over z)
__global__ __launch_bounds__(256) void transpose_k(const float* __restrict__ src,
    ushort* __restrict__ dst, int R, int C, size_t sBatch, size_t dBatch)
{
  __shared__ ushort tile[32][33];
  src += (size_t)blockIdx.z * sBatch;
  dst += (size_t)blockIdx.z * dBatch;
  int tx = threadIdx.x & 31, ty = threadIdx.x >> 5;   // 32 x 8
  int r0 = blockIdx.y * 32, c0 = blockIdx.x * 32;
  #pragma unroll
  for (int i = 0; i < 4; ++i){
    int r = r0 + ty + i*8;
    tile[ty + i*8][tx] = f2b(src[(size_t)r * C + c0 + tx]);
  }
  __syncthreads();
  #pragma unroll
  for (int i = 0; i < 4; ++i){
    int c = c0 + ty + i*8;
    dst[(size_t)c * R + r0 + tx] = tile[tx][ty + i*8];
  }
}

__global__ __launch_bounds__(256) void pack_bqkv(const float* __restrict__ bq,
    const float* __restrict__ bk, const float* __restrict__ bv, float* __restrict__ dst)
{
  int i = blockIdx.x * 256 + threadIdx.x;      // < L_*1536
  int l = i / 1536, n = i % 1536;
  float v = (n < 512) ? bq[l*512 + n] : (n < 1024 ? bk[l*512 + n - 512] : bv[l*512 + n - 1024]);
  dst[i] = v;
}

// ---------------------------------------------------------------- GEMM (B^T)
// C[M,N] = A[M,K(part)] @ Bt[N,K]^T (+ bias on z==0)
// EPI: 0=bf16, 1=gelu->bf16, 2=tanh->bf16, 3=f32 (split-K partial at z*M*N)
// BM=64, BN=128, BK=32; 4 waves; 3-buffer counted-vmcnt pipeline;
// XOR-swizzled LDS (inverse-swizzled global source, swizzled reads).
template<int EPI>
__global__ __launch_bounds__(256, 4) void gemm_bt(
    const ushort* __restrict__ A, const ushort* __restrict__ Bt,
    const float* __restrict__ bias, ushort* __restrict__ o16,
    float* __restrict__ o32, int M, int N, int K, int Klen)
{
  __shared__ ushort lds[3*6144];        // 3 bufs x (A 2048 + B 4096 elems) = 36 KB
  const int tid = threadIdx.x;
  const int bm = blockIdx.y * 64, bn = blockIdx.x * 128;
  const int kbeg = blockIdx.z * Klen;
  const int wave = tid >> 6, lane = tid & 63;
  const int wr = (wave >> 1) * 32, wc = (wave & 1) * 64;
  const int lr = lane & 15, lg = lane >> 4;
  const int lkS = (lg ^ ((lr >> 1) & 3)) * 8;      // swizzled read chunk (lane-const)
  f32x4 acc[2][4] = {};

  // staging: thread t -> row t>>2; SOURCE chunk is inverse-swizzled so that
  // linear DMA dest + swizzled read = identity (rule: both-sides-or-neither).
  const int srow = tid >> 2;
  const int schk = (((tid & 3) ^ ((tid >> 3) & 3))) * 8;
  const ushort* Ag  = A  + (size_t)(bm + srow) * K + kbeg + schk;
  const ushort* Bg0 = Bt + (size_t)(bn + srow) * K + kbeg + schk;
  const ushort* Bg1 = Bt + (size_t)(bn + 64 + srow) * K + kbeg + schk;

  const int nIter = Klen >> 5;
  auto issueTile = [&](int t, int buf){
    int k0 = t << 5;
    ushort* d = &lds[0] + buf*6144 + tid*8;
    async16(Ag  + k0, d);
    async16(Bg0 + k0, d + 2048);
    async16(Bg1 + k0, d + 4096);
  };

  // prologue: tiles 0 and 1 in flight
  issueTile(0, 0);
  issueTile(1, 1);

  int cb = 0;                           // buffer holding tile t
  for (int t = 0; t < nIter; ++t){
    int ib = cb + 2; if (ib >= 3) ib -= 3;
    if (t + 2 < nIter) issueTile(t + 2, ib);
    if (t + 2 < nIter)      asm volatile("s_waitcnt vmcnt(6)" ::: "memory");
    else if (t + 1 < nIter) asm volatile("s_waitcnt vmcnt(3)" ::: "memory");
    else                    asm volatile("s_waitcnt vmcnt(0)" ::: "memory");
    __builtin_amdgcn_sched_barrier(0);
    __builtin_amdgcn_s_barrier();       // tile t visible to all waves
    const ushort* bufp = &lds[0] + cb*6144;
    short8v af[2], bfr[4];
    #pragma unroll
    for (int mi = 0; mi < 2; ++mi)
      af[mi] = *(const short8v*)(bufp + (wr + mi*16 + lr)*32 + lkS);
    #pragma unroll
    for (int nj = 0; nj < 4; ++nj)
      bfr[nj] = *(const short8v*)(bufp + 2048 + (wc + nj*16 + lr)*32 + lkS);
    #pragma unroll
    for (int mi = 0; mi < 2; ++mi)
      #pragma unroll
      for (int nj = 0; nj < 4; ++nj)
        acc[mi][nj] = __builtin_amdgcn_mfma_f32_16x16x32_bf16(af[mi], bfr[nj], acc[mi][nj], 0, 0, 0);
    __builtin_amdgcn_s_barrier();       // all reads of buf cb done before reuse
    cb = cb + 1; if (cb == 3) cb = 0;
  }

  const float bscale = (blockIdx.z == 0) ? 1.0f : 0.0f;
  #pragma unroll
  for (int mi = 0; mi < 2; ++mi){
    #pragma unroll
    for (int nj = 0; nj < 4; ++nj){
      int col = bn + wc + nj*16 + lr;
      float bv = bias[col] * bscale;
      #pragma unroll
      for (int j = 0; j < 4; ++j){
        int row = bm + wr + mi*16 + lg*4 + j;
        float v = acc[mi][nj][j] + bv;
        if (EPI == 1) v = 0.5f * v * (1.0f + erff(v * 0.70710678118654752f));
        if (EPI == 2) v = tanhf(v);
        if (EPI == 3) o32[(size_t)blockIdx.z*M*N + (size_t)row * N + col] = v;
        else          o16[(size_t)row * N + col] = f2b(v);
      }
    }
  }
}

// ---------------------------------------------------------------- LayerNorm
__device__ __forceinline__ void block_ln_stats(float v0, float v1, float* red,
                                               float& mean, float& rstd)
{
  int tid = threadIdx.x, wave = tid >> 6, lane = tid & 63;
  float sm = v0 + v1;
  float sq = v0*v0 + v1*v1;
  #pragma unroll
  for (int o = 32; o > 0; o >>= 1){ sm += __shfl_xor(sm, o); sq += __shfl_xor(sq, o); }
  if (lane == 0){ red[wave] = sm; red[4 + wave] = sq; }
  __syncthreads();
  float S = red[0] + red[1] + red[2] + red[3];
  float Q = red[4] + red[5] + red[6] + red[7];
  mean = S * (1.0f / 512.0f);
  float var = Q * (1.0f / 512.0f) - mean*mean;
  if (var < 0.f) var = 0.f;
  rstd = rsqrtf(var + 1e-12f);
}

// embeddings LN (float2 vectorized): x,pos f32 -> out bf16 + f32 shadow
__global__ __launch_bounds__(256) void embed_ln(const float* __restrict__ x,
    const float* __restrict__ pos, const float* __restrict__ g,
    const float* __restrict__ bb, ushort* __restrict__ out16, float* __restrict__ out32)
{
  __shared__ float red[8];
  int row = blockIdx.x, tid = threadIdx.x;
  int s = row & (S_ - 1);
  const size_t base = (size_t)row*H_ + tid*2;
  float2 xv = *(const float2*)(x + base);
  float2 pv = *(const float2*)(pos + (size_t)s*H_ + tid*2);
  float v0 = xv.x + pv.x, v1 = xv.y + pv.y;
  float mean, rstd;
  block_ln_stats(v0, v1, red, mean, rstd);
  float2 gv = *(const float2*)(g + tid*2);
  float2 bv = *(const float2*)(bb + tid*2);
  float r0 = (v0 - mean)*rstd*gv.x + bv.x;
  float r1 = (v1 - mean)*rstd*gv.y + bv.y;
  ushort2 o2; o2.x = f2b(r0); o2.y = f2b(r1);
  *(ushort2*)(out16 + base) = o2;
  float2 f2v; f2v.x = r0; f2v.y = r1;
  *(float2*)(out32 + base) = f2v;
}

// LN(t0 + t1 + res32) float2 vectorized
__global__ __launch_bounds__(256) void ln_res(const float* __restrict__ t,
    const float* __restrict__ res, const float* __restrict__ g,
    const float* __restrict__ bb, ushort* __restrict__ out16, float* __restrict__ out32)
{
  __shared__ float red[8];
  int row = blockIdx.x, tid = threadIdx.x;
  const size_t MN = (size_t)M_*H_;
  const size_t base = (size_t)row*H_ + tid*2;
  float2 t0 = *(const float2*)(t + base);
  float2 t1v = *(const float2*)(t + MN + base);
  float2 rv = *(const float2*)(res + base);
  float v0 = t0.x + t1v.x + rv.x;
  float v1 = t0.y + t1v.y + rv.y;
  float mean, rstd;
  block_ln_stats(v0, v1, red, mean, rstd);
  float2 gv = *(const float2*)(g + tid*2);
  float2 bv = *(const float2*)(bb + tid*2);
  float r0 = (v0 - mean)*rstd*gv.x + bv.x;
  float r1 = (v1 - mean)*rstd*gv.y + bv.y;
  ushort2 o2; o2.x = f2b(r0); o2.y = f2b(r1);
  *(ushort2*)(out16 + base) = o2;
  float2 f2v; f2v.x = r0; f2v.y = r1;
  *(float2*)(out32 + base) = f2v;
}

// ---------------------------------------------------------------- attention (MFMA)
// qkv: [B*S][1536] bf16 (q|k|v each 512). Block: 256 thr (4 waves) = one
// (b,h) x 64-row Q-block. Keys/values: 128-wide chunk [s0-32, s0+95].
__global__ __launch_bounds__(256) void attn_mfma(const ushort* __restrict__ qkv,
    const float* __restrict__ mask, ushort* __restrict__ ctx)
{
  __shared__ ushort K_lds[128][72];   // [key c][k]   (pad 72: 2-way free)
  __shared__ ushort Vt[64][136];      // [d][key c]   (pad 136)
  __shared__ ushort P_lds[64][136];   // [q row][key c]
  __shared__ float  kb[128];

  const int tid = threadIdx.x, wave = tid >> 6, lane = tid & 63;
  const int hh = blockIdx.y & (NH_ - 1), b = blockIdx.y >> 3;
  const int s0 = blockIdx.x * 64;
  const size_t rb = (size_t)b * S_;

  // ---- stage K rows c=0..127 and V^T
  const int ch = tid & 7;             // 16B chunk within 64-d row
  const int rr = tid >> 3;            // 0..31
  #pragma unroll
  for (int it = 0; it < 4; ++it){
    int c = rr + it*32;
    int j = s0 - 32 + c;
    int jc = min(max(j, 0), S_ - 1);
    const size_t rowb = (rb + jc) * 1536 + hh*64 + ch*8;
    *(short8v*)(&K_lds[c][ch*8]) = *(const short8v*)(qkv + rowb + 512);
    short8v vv = *(const short8v*)(qkv + rowb + 1024);
    #pragma unroll
    for (int t = 0; t < 8; ++t){      // staggered transpose write (<=2-way)
      int tt = (t + ch) & 7;
      Vt[ch*8 + tt][c] = (ushort)vv[tt];
    }
  }
  if (tid < 128){
    int j = s0 - 32 + tid;
    kb[tid] = (j >= 0 && j < S_) ? (1.0f - mask[rb + j]) * (-10000.0f) : -1e30f;
  }
  __syncthreads();

  const int wq0 = wave * 16;
  const int lr = lane & 15, lg = lane >> 4, lk = lg * 8;

  // Q fragments (A): row = wq0+lr, k = lk..lk+7 (+32 for second frag)
  const ushort* qbase = qkv + (rb + s0 + wq0 + lr) * 1536 + hh*64;
  short8v aq0 = *(const short8v*)(qbase + lk);
  short8v aq1 = *(const short8v*)(qbase + 32 + lk);

  // scores: 16x128 strip per wave
  f32x4 sacc[8];
  #pragma unroll
  for (int cn = 0; cn < 8; ++cn){
    short8v bk0 = *(const short8v*)(&K_lds[cn*16 + lr][lk]);
    short8v bk1 = *(const short8v*)(&K_lds[cn*16 + lr][32 + lk]);
    f32x4 z = {0.f, 0.f, 0.f, 0.f};
    z = __builtin_amdgcn_mfma_f32_16x16x32_bf16(aq0, bk0, z, 0, 0, 0);
    z = __builtin_amdgcn_mfma_f32_16x16x32_bf16(aq1, bk1, z, 0, 0, 0);
    sacc[cn] = z;
  }

  // row softmax: lane holds cols cn*16+lr of rows wq0 + lg*4 + jr
  #pragma unroll
  for (int jr = 0; jr < 4; ++jr){
    const int R = wq0 + lg*4 + jr;     // row within 64-block
    float v[8], mx = -1e30f;
    #pragma unroll
    for (int cn = 0; cn < 8; ++cn){
      int c = cn*16 + lr;
      float sc = sacc[cn][jr] * 0.125f + kb[c];
      if (c < R || c > R + 64) sc = -1e30f;   // band mask
      v[cn] = sc;
      mx = fmaxf(mx, sc);
    }
    #pragma unroll
    for (int o = 1; o < 16; o <<= 1) mx = fmaxf(mx, __shfl_xor(mx, o));
    float sum = 0.f;
    #pragma unroll
    for (int cn = 0; cn < 8; ++cn){ v[cn] = __expf(v[cn] - mx); sum += v[cn]; }
    #pragma unroll
    for (int o = 1; o < 16; o <<= 1) sum += __shfl_xor(sum, o);
    float qm = mask[rb + s0 + R];
    float inv = ((qm < 0.999f) ? 0.0f : 1.0f) / sum;
    #pragma unroll
    for (int cn = 0; cn < 8; ++cn)
      P_lds[R][cn*16 + lr] = f2b(v[cn] * inv);
  }
  // P write->read is within-wave (rows wq0..wq0+15); LDS ops are in-order per wave.

  // PV: ctx[16x64 strip] = P[16x128] @ V[128x64]
  short8v ap[4];
  #pragma unroll
  for (int ks = 0; ks < 4; ++ks)
    ap[ks] = *(const short8v*)(&P_lds[wq0 + lr][ks*32 + lk]);
  #pragma unroll
  for (int dn = 0; dn < 4; ++dn){
    f32x4 z = {0.f, 0.f, 0.f, 0.f};
    #pragma unroll
    for (int ks = 0; ks < 4; ++ks){
      short8v bv = *(const short8v*)(&Vt[dn*16 + lr][ks*32 + lk]);
      z = __builtin_amdgcn_mfma_f32_16x16x32_bf16(ap[ks], bv, z, 0, 0, 0);
    }
    #pragma unroll
    for (int jr = 0; jr < 4; ++jr){
      int R = wq0 + lg*4 + jr;
      ctx[(rb + s0 + R)*H_ + hh*64 + dn*16 + lr] = f2b(z[jr]);
    }
  }
}

// ---------------------------------------------------------------- pooling
__global__ __launch_bounds__(256) void pool_logit(const ushort* __restrict__ e,
    const float* __restrict__ w2, const float* __restrict__ b2p,
    const float* __restrict__ mask, float* __restrict__ alpha)
{
  int tid = threadIdx.x, wave = tid >> 6, lane = tid & 63;
  int r = blockIdx.x * 4 + wave;
  short8v ev = *(const short8v*)(e + (size_t)r*H_ + lane*8);
  float sacc = 0.f;
  #pragma unroll
  for (int j = 0; j < 8; ++j) sacc += b2f((ushort)ev[j]) * w2[lane*8 + j];
  #pragma unroll
  for (int o = 32; o > 0; o >>= 1) sacc += __shfl_xor(sacc, o);
  if (lane == 0){
    float logit = sacc + b2p[0];
    alpha[r] = __expf(logit) * mask[r];
  }
}

__global__ __launch_bounds__(256) void pool_sum(const float* __restrict__ alpha,
                                                float* __restrict__ invsum)
{
  __shared__ float red[4];
  int b = blockIdx.x, tid = threadIdx.x, wave = tid >> 6, lane = tid & 63;
  float s = 0.f;
  for (int k = tid; k < S_; k += 256) s += alpha[b*S_ + k];
  #pragma unroll
  for (int o = 32; o > 0; o >>= 1) s += __shfl_xor(s, o);
  if (lane == 0) red[wave] = s;
  __syncthreads();
  if (tid == 0) invsum[b] = 1.0f / (red[0] + red[1] + red[2] + red[3] + 1e-8f);
}

// deterministic chunked weighted sum (float2): outacc[chunk][b][h]
__global__ __launch_bounds__(256) void pool_wsum(const float* __restrict__ x,
    const float* __restrict__ alpha, float* __restrict__ out_acc)
{
  int chunk = blockIdx.x, b = blockIdx.y, tid = threadIdx.x;
  int s0 = chunk * 128;
  int c0 = tid * 2;
  float a0 = 0.f, a1 = 0.f;
  for (int i = 0; i < 128; ++i){
    int srow = s0 + i;
    float al = alpha[b*S_ + srow];
    float2 xv = *(const float2*)(x + (size_t)(b*S_ + srow)*H_ + c0);
    a0 += xv.x * al;
    a1 += xv.y * al;
  }
  float2 o; o.x = a0; o.y = a1;
  *(float2*)(out_acc + (size_t)chunk*B_*H_ + b*H_ + c0) = o;
}

__global__ __launch_bounds__(256) void pool_final(const float* __restrict__ out_acc,
    const float* __restrict__ invsum, float* __restrict__ out)
{
  int i = blockIdx.x * 256 + threadIdx.x;
  if (i < B_*H_){
    int b = i >> 9;
    float s = 0.f;
    #pragma unroll
    for (int c = 0; c < 16; ++c) s += out_acc[(size_t)c*B_*H_ + i];
    out[i] = s * invsum[b];
  }
}

// ---------------------------------------------------------------- launch
extern "C" void kernel_launch(void* const* d_in, const int* in_sizes, int n_in,
                              void* d_out, int out_size, void* d_ws, size_t ws_size,
                              hipStream_t stream)
{
  const float* input_embs = (const float*)d_in[0];
  const float* mask       = (const float*)d_in[1];
  const float* pos        = (const float*)d_in[2];
  const float* ln_emb_g   = (const float*)d_in[3];
  const float* ln_emb_b   = (const float*)d_in[4];
  const float* Wq  = (const float*)d_in[5];
  const float* bq  = (const float*)d_in[6];
  const float* Wk  = (const float*)d_in[7];
  const float* bk  = (const float*)d_in[8];
  const float* Wv  = (const float*)d_in[9];
  const float* bv  = (const float*)d_in[10];
  const float* Wo  = (const float*)d_in[11];
  const float* bo  = (const float*)d_in[12];
  const float* ln1_g = (const float*)d_in[13];
  const float* ln1_b = (const float*)d_in[14];
  const float* Wi  = (const float*)d_in[15];
  const float* bi  = (const float*)d_in[16];
  const float* Wo2 = (const float*)d_in[17];
  const float* bo2 = (const float*)d_in[18];
  const float* ln2_g = (const float*)d_in[19];
  const float* ln2_b = (const float*)d_in[20];
  const float* pW1 = (const float*)d_in[21];
  const float* pb1 = (const float*)d_in[22];
  const float* pW2 = (const float*)d_in[23];
  const float* pb2 = (const float*)d_in[24];

  char* ws = (char*)d_ws;
  size_t off = 0;
  auto alloc = [&](size_t bytes)->char*{
    char* p = ws + off; off += (bytes + 255) & ~(size_t)255; return p;
  };
  ushort* WqkvT  = (ushort*)alloc((size_t)L_*1536*512*2);
  ushort* WoT    = (ushort*)alloc((size_t)L_*512*512*2);
  ushort* WiT    = (ushort*)alloc((size_t)L_*2048*512*2);
  ushort* Wo2T   = (ushort*)alloc((size_t)L_*512*2048*2);
  ushort* pW1T   = (ushort*)alloc((size_t)512*512*2);
  float*  bqkv   = (float*)alloc((size_t)L_*1536*4);
  ushort* h16    = (ushort*)alloc((size_t)M_*H_*2);
  float*  h32    = (float*)alloc((size_t)M_*H_*4);
  ushort* qkv    = (ushort*)alloc((size_t)M_*1536*2);
  ushort* ctx    = (ushort*)alloc((size_t)M_*H_*2);
  ushort* attn16 = (ushort*)alloc((size_t)M_*H_*2);
  float*  attn32 = (float*)alloc((size_t)M_*H_*4);
  ushort* inter  = (ushort*)alloc((size_t)M_*INTER_*2);
  float*  t1     = (float*)alloc((size_t)2*M_*H_*4);   // 2 split-K partials
  float*  alpha  = (float*)alloc((size_t)M_*4);
  float*  invsum = (float*)alloc(256);
  float*  outacc = (float*)alloc((size_t)16*B_*H_*4);

  dim3 tb(256);
  transpose_k<<<dim3(16,16,L_), tb, 0, stream>>>(Wq, WqkvT,            512,  512, (size_t)512*512,  (size_t)1536*512);
  transpose_k<<<dim3(16,16,L_), tb, 0, stream>>>(Wk, WqkvT + 512*512,  512,  512, (size_t)512*512,  (size_t)1536*512);
  transpose_k<<<dim3(16,16,L_), tb, 0, stream>>>(Wv, WqkvT + 1024*512, 512,  512, (size_t)512*512,  (size_t)1536*512);
  transpose_k<<<dim3(16,16,L_), tb, 0, stream>>>(Wo, WoT,              512,  512, (size_t)512*512,  (size_t)512*512);
  transpose_k<<<dim3(64,16,L_), tb, 0, stream>>>(Wi, WiT,              512, 2048, (size_t)512*2048, (size_t)2048*512);
  transpose_k<<<dim3(16,64,L_), tb, 0, stream>>>(Wo2, Wo2T,           2048,  512, (size_t)2048*512, (size_t)512*2048);
  transpose_k<<<dim3(16,16,1),  tb, 0, stream>>>(pW1, pW1T,            512,  512, 0, 0);
  pack_bqkv<<<dim3(L_*1536/256), tb, 0, stream>>>(bq, bk, bv, bqkv);

  embed_ln<<<dim3(M_), tb, 0, stream>>>(input_embs, pos, ln_emb_g, ln_emb_b, h16, h32);

  for (int l = 0; l < L_; ++l){
    gemm_bt<0><<<dim3(12,64,1), tb, 0, stream>>>(h16, WqkvT + (size_t)l*1536*512, bqkv + l*1536,
                                                 qkv, nullptr, M_, 1536, 512, 512);
    attn_mfma<<<dim3(S_/64, B_*NH_), tb, 0, stream>>>(qkv, mask, ctx);
    gemm_bt<3><<<dim3(4,64,2), tb, 0, stream>>>(ctx, WoT + (size_t)l*512*512, bo + l*512,
                                                nullptr, t1, M_, 512, 512, 256);
    ln_res<<<dim3(M_), tb, 0, stream>>>(t1, h32, ln1_g + l*512, ln1_b + l*512, attn16, attn32);
    gemm_bt<1><<<dim3(16,64,1), tb, 0, stream>>>(attn16, WiT + (size_t)l*2048*512, bi + l*2048,
                                                 inter, nullptr, M_, 2048, 512, 512);
    gemm_bt<3><<<dim3(4,64,2), tb, 0, stream>>>(inter, Wo2T + (size_t)l*512*2048, bo2 + l*512,
                                                nullptr, t1, M_, 512, 2048, 1024);
    ln_res<<<dim3(M_), tb, 0, stream>>>(t1, attn32, ln2_g + l*512, ln2_b + l*512, h16, h32);
  }

  // pooling: e = tanh(h @ pW1 + pb1)  (reuse ctx buffer for e)
  gemm_bt<2><<<dim3(4,64,1), tb, 0, stream>>>(h16, pW1T, pb1, ctx, nullptr, M_, 512, 512, 512);
  pool_logit<<<dim3(M_/4), tb, 0, stream>>>(ctx, pW2, pb2, mask, alpha);
  pool_sum<<<dim3(B_), tb, 0, stream>>>(alpha, invsum);
  pool_wsum<<<dim3(16, B_), tb, 0, stream>>>(h32, alpha, outacc);
  pool_final<<<dim3((B_*H_ + 255)/256), tb, 0, stream>>>(outacc, invsum, (float*)d_out);
}

// Round 9
// 410.954 us; speedup vs baseline: 1.1564x; 1.0117x over previous
//
#include <hip/hip_runtime.h>
#include <hip/hip_bf16.h>
#include <math.h>

#define B_ 2
#define S_ 2048
#define H_ 512
#define NH_ 8
#define HD_ 64
#define L_ 4
#define INTER_ 2048
#define W1_ 32
#define WB_ 65
#define M_ (B_*S_)   // 4096

typedef __attribute__((ext_vector_type(8))) short short8v;
typedef __attribute__((ext_vector_type(4))) float f32x4;

__device__ __forceinline__ float b2f(ushort u){ return __uint_as_float(((unsigned)u)<<16); }
__device__ __forceinline__ ushort f2b(float f){
  unsigned u = __float_as_uint(f);
  unsigned r = (u + 0x7fffu + ((u>>16)&1u)) >> 16;
  return (ushort)r;
}

// async global->LDS, 16B per lane (linear LDS dest = base + lane*16).
__device__ __forceinline__ void async16(const ushort* g, ushort* l){
  __builtin_amdgcn_global_load_lds(
      (const __attribute__((address_space(1))) unsigned int*)g,
      (__attribute__((address_space(3))) unsigned int*)l, 16, 0, 0);
}

// ---------------------------------------------------------------- transpose+cvt
// src [R][C] f32 row-major -> dst [C][R] bf16 row-major (batched over z)
__global__ __launch_bounds__(256) void transpose_k(const float* __restrict__ src,
    ushort* __restrict__ dst, int R, int C, size_t sBatch, size_t dBatch)
{
  __shared__ ushort tile[32][33];
  src += (size_t)blockIdx.z * sBatch;
  dst += (size_t)blockIdx.z * dBatch;
  int tx = threadIdx.x & 31, ty = threadIdx.x >> 5;   // 32 x 8
  int r0 = blockIdx.y * 32, c0 = blockIdx.x * 32;
  #pragma unroll
  for (int i = 0; i < 4; ++i){
    int r = r0 + ty + i*8;
    tile[ty + i*8][tx] = f2b(src[(size_t)r * C + c0 + tx]);
  }
  __syncthreads();
  #pragma unroll
  for (int i = 0; i < 4; ++i){
    int c = c0 + ty + i*8;
    dst[(size_t)c * R + r0 + tx] = tile[tx][ty + i*8];
  }
}

__global__ __launch_bounds__(256) void pack_bqkv(const float* __restrict__ bq,
    const float* __restrict__ bk, const float* __restrict__ bv, float* __restrict__ dst)
{
  int i = blockIdx.x * 256 + threadIdx.x;      // < L_*1536
  int l = i / 1536, n = i % 1536;
  float v = (n < 512) ? bq[l*512 + n] : (n < 1024 ? bk[l*512 + n - 512] : bv[l*512 + n - 1024]);
  dst[i] = v;
}

// ---------------------------------------------------------------- GEMM (B^T)
// C[M,N] = A[M,K(part)] @ Bt[N,K]^T (+ bias on z==0)
// EPI: 0=bf16, 1=gelu->bf16, 2=tanh->bf16, 3=f32 (split-K partial at z*M*N)
// BM x 128 tile (BM = 64 or 128), BK=32; 4 waves; 3-buffer counted-vmcnt
// pipeline; XOR-swizzled LDS (inverse-swizzled global source, swizzled reads).
template<int EPI, int BM>
__global__ __launch_bounds__(256, (BM == 64) ? 4 : 3) void gemm_bt(
    const ushort* __restrict__ A, const ushort* __restrict__ Bt,
    const float* __restrict__ bias, ushort* __restrict__ o16,
    float* __restrict__ o32, int M, int N, int K, int Klen)
{
  constexpr int ABUF = BM * 32;          // elems per A tile
  constexpr int BUFE = ABUF + 4096;      // + B tile (128x32)
  constexpr int MI = BM / 32;            // acc rows per wave
  constexpr int AL = BM / 64;            // A staging rounds per tile
  __shared__ ushort lds[3 * BUFE];
  const int tid = threadIdx.x;
  const int bm = blockIdx.y * BM, bn = blockIdx.x * 128;
  const int kbeg = blockIdx.z * Klen;
  const int wave = tid >> 6, lane = tid & 63;
  const int wr = (wave >> 1) * (BM / 2), wc = (wave & 1) * 64;
  const int lr = lane & 15, lg = lane >> 4;
  const int lkS = (lg ^ ((lr >> 1) & 3)) * 8;      // swizzled read chunk (lane-const)
  f32x4 acc[MI][4] = {};

  // staging: thread t -> row t>>2; SOURCE chunk is inverse-swizzled so that
  // linear DMA dest + swizzled read = identity (both-sides-or-neither).
  const int srow = tid >> 2;
  const int schk = (((tid & 3) ^ ((tid >> 3) & 3))) * 8;
  const ushort* Ag  = A  + (size_t)(bm + srow) * K + kbeg + schk;
  const ushort* Bg0 = Bt + (size_t)(bn + srow) * K + kbeg + schk;
  const ushort* Bg1 = Bt + (size_t)(bn + 64 + srow) * K + kbeg + schk;

  const int nIter = Klen >> 5;
  auto issueTile = [&](int t, int buf){
    int k0 = t << 5;
    ushort* d = &lds[0] + buf*BUFE + tid*8;
    #pragma unroll
    for (int r = 0; r < AL; ++r)
      async16(Ag + (size_t)r*64*K + k0, d + r*2048);
    async16(Bg0 + k0, d + ABUF);
    async16(Bg1 + k0, d + ABUF + 2048);
  };

  // prologue: tiles 0 and 1 in flight
  issueTile(0, 0);
  issueTile(1, 1);

  int cb = 0;                           // buffer holding tile t
  for (int t = 0; t < nIter; ++t){
    int ib = cb + 2; if (ib >= 3) ib -= 3;
    if (t + 2 < nIter) issueTile(t + 2, ib);
    if constexpr (BM == 64){
      if (t + 2 < nIter)      asm volatile("s_waitcnt vmcnt(6)" ::: "memory");
      else if (t + 1 < nIter) asm volatile("s_waitcnt vmcnt(3)" ::: "memory");
      else                    asm volatile("s_waitcnt vmcnt(0)" ::: "memory");
    } else {
      if (t + 2 < nIter)      asm volatile("s_waitcnt vmcnt(8)" ::: "memory");
      else if (t + 1 < nIter) asm volatile("s_waitcnt vmcnt(4)" ::: "memory");
      else                    asm volatile("s_waitcnt vmcnt(0)" ::: "memory");
    }
    __builtin_amdgcn_sched_barrier(0);
    __builtin_amdgcn_s_barrier();       // tile t visible to all waves
    const ushort* bufp = &lds[0] + cb*BUFE;
    short8v af[MI], bfr[4];
    #pragma unroll
    for (int mi = 0; mi < MI; ++mi)
      af[mi] = *(const short8v*)(bufp + (wr + mi*16 + lr)*32 + lkS);
    #pragma unroll
    for (int nj = 0; nj < 4; ++nj)
      bfr[nj] = *(const short8v*)(bufp + ABUF + (wc + nj*16 + lr)*32 + lkS);
    #pragma unroll
    for (int mi = 0; mi < MI; ++mi)
      #pragma unroll
      for (int nj = 0; nj < 4; ++nj)
        acc[mi][nj] = __builtin_amdgcn_mfma_f32_16x16x32_bf16(af[mi], bfr[nj], acc[mi][nj], 0, 0, 0);
    __builtin_amdgcn_s_barrier();       // all reads of buf cb done before reuse
    cb = cb + 1; if (cb == 3) cb = 0;
  }

  const float bscale = (blockIdx.z == 0) ? 1.0f : 0.0f;
  #pragma unroll
  for (int mi = 0; mi < MI; ++mi){
    #pragma unroll
    for (int nj = 0; nj < 4; ++nj){
      int col = bn + wc + nj*16 + lr;
      float bv = bias[col] * bscale;
      #pragma unroll
      for (int j = 0; j < 4; ++j){
        int row = bm + wr + mi*16 + lg*4 + j;
        float v = acc[mi][nj][j] + bv;
        if (EPI == 1) v = 0.5f * v * (1.0f + erff(v * 0.70710678118654752f));
        if (EPI == 2) v = tanhf(v);
        if (EPI == 3) o32[(size_t)blockIdx.z*M*N + (size_t)row * N + col] = v;
        else          o16[(size_t)row * N + col] = f2b(v);
      }
    }
  }
}

// ---------------------------------------------------------------- LayerNorm
__device__ __forceinline__ void block_ln_stats(float v0, float v1, float* red,
                                               float& mean, float& rstd)
{
  int tid = threadIdx.x, wave = tid >> 6, lane = tid & 63;
  float sm = v0 + v1;
  float sq = v0*v0 + v1*v1;
  #pragma unroll
  for (int o = 32; o > 0; o >>= 1){ sm += __shfl_xor(sm, o); sq += __shfl_xor(sq, o); }
  if (lane == 0){ red[wave] = sm; red[4 + wave] = sq; }
  __syncthreads();
  float S = red[0] + red[1] + red[2] + red[3];
  float Q = red[4] + red[5] + red[6] + red[7];
  mean = S * (1.0f / 512.0f);
  float var = Q * (1.0f / 512.0f) - mean*mean;
  if (var < 0.f) var = 0.f;
  rstd = rsqrtf(var + 1e-12f);
}

// embeddings LN (float2 vectorized): x,pos f32 -> out bf16 + f32 shadow
__global__ __launch_bounds__(256) void embed_ln(const float* __restrict__ x,
    const float* __restrict__ pos, const float* __restrict__ g,
    const float* __restrict__ bb, ushort* __restrict__ out16, float* __restrict__ out32)
{
  __shared__ float red[8];
  int row = blockIdx.x, tid = threadIdx.x;
  int s = row & (S_ - 1);
  const size_t base = (size_t)row*H_ + tid*2;
  float2 xv = *(const float2*)(x + base);
  float2 pv = *(const float2*)(pos + (size_t)s*H_ + tid*2);
  float v0 = xv.x + pv.x, v1 = xv.y + pv.y;
  float mean, rstd;
  block_ln_stats(v0, v1, red, mean, rstd);
  float2 gv = *(const float2*)(g + tid*2);
  float2 bv = *(const float2*)(bb + tid*2);
  float r0 = (v0 - mean)*rstd*gv.x + bv.x;
  float r1 = (v1 - mean)*rstd*gv.y + bv.y;
  ushort2 o2; o2.x = f2b(r0); o2.y = f2b(r1);
  *(ushort2*)(out16 + base) = o2;
  float2 f2v; f2v.x = r0; f2v.y = r1;
  *(float2*)(out32 + base) = f2v;
}

// LN(t0 + t1 + res32) float2 vectorized
__global__ __launch_bounds__(256) void ln_res(const float* __restrict__ t,
    const float* __restrict__ res, const float* __restrict__ g,
    const float* __restrict__ bb, ushort* __restrict__ out16, float* __restrict__ out32)
{
  __shared__ float red[8];
  int row = blockIdx.x, tid = threadIdx.x;
  const size_t MN = (size_t)M_*H_;
  const size_t base = (size_t)row*H_ + tid*2;
  float2 t0 = *(const float2*)(t + base);
  float2 t1v = *(const float2*)(t + MN + base);
  float2 rv = *(const float2*)(res + base);
  float v0 = t0.x + t1v.x + rv.x;
  float v1 = t0.y + t1v.y + rv.y;
  float mean, rstd;
  block_ln_stats(v0, v1, red, mean, rstd);
  float2 gv = *(const float2*)(g + tid*2);
  float2 bv = *(const float2*)(bb + tid*2);
  float r0 = (v0 - mean)*rstd*gv.x + bv.x;
  float r1 = (v1 - mean)*rstd*gv.y + bv.y;
  ushort2 o2; o2.x = f2b(r0); o2.y = f2b(r1);
  *(ushort2*)(out16 + base) = o2;
  float2 f2v; f2v.x = r0; f2v.y = r1;
  *(float2*)(out32 + base) = f2v;
}

// ---------------------------------------------------------------- attention (MFMA)
// qkv: [B*S][1536] bf16 (q|k|v each 512). Block: 256 thr (4 waves) = one
// (b,h) x 64-row Q-block. Keys/values: 128-wide chunk [s0-32, s0+95].
__global__ __launch_bounds__(256) void attn_mfma(const ushort* __restrict__ qkv,
    const float* __restrict__ mask, ushort* __restrict__ ctx)
{
  __shared__ ushort K_lds[128][72];   // [key c][k]   (pad 72: 2-way free)
  __shared__ ushort Vt[64][136];      // [d][key c]   (pad 136)
  __shared__ ushort P_lds[64][136];   // [q row][key c]
  __shared__ float  kb[128];

  const int tid = threadIdx.x, wave = tid >> 6, lane = tid & 63;
  const int hh = blockIdx.y & (NH_ - 1), b = blockIdx.y >> 3;
  const int s0 = blockIdx.x * 64;
  const size_t rb = (size_t)b * S_;

  // ---- stage K rows c=0..127 and V^T
  const int ch = tid & 7;             // 16B chunk within 64-d row
  const int rr = tid >> 3;            // 0..31
  #pragma unroll
  for (int it = 0; it < 4; ++it){
    int c = rr + it*32;
    int j = s0 - 32 + c;
    int jc = min(max(j, 0), S_ - 1);
    const size_t rowb = (rb + jc) * 1536 + hh*64 + ch*8;
    *(short8v*)(&K_lds[c][ch*8]) = *(const short8v*)(qkv + rowb + 512);
    short8v vv = *(const short8v*)(qkv + rowb + 1024);
    #pragma unroll
    for (int t = 0; t < 8; ++t){      // staggered transpose write (<=2-way)
      int tt = (t + ch) & 7;
      Vt[ch*8 + tt][c] = (ushort)vv[tt];
    }
  }
  if (tid < 128){
    int j = s0 - 32 + tid;
    kb[tid] = (j >= 0 && j < S_) ? (1.0f - mask[rb + j]) * (-10000.0f) : -1e30f;
  }
  __syncthreads();

  const int wq0 = wave * 16;
  const int lr = lane & 15, lg = lane >> 4, lk = lg * 8;

  // Q fragments (A): row = wq0+lr, k = lk..lk+7 (+32 for second frag)
  const ushort* qbase = qkv + (rb + s0 + wq0 + lr) * 1536 + hh*64;
  short8v aq0 = *(const short8v*)(qbase + lk);
  short8v aq1 = *(const short8v*)(qbase + 32 + lk);

  // scores: 16x128 strip per wave
  f32x4 sacc[8];
  #pragma unroll
  for (int cn = 0; cn < 8; ++cn){
    short8v bk0 = *(const short8v*)(&K_lds[cn*16 + lr][lk]);
    short8v bk1 = *(const short8v*)(&K_lds[cn*16 + lr][32 + lk]);
    f32x4 z = {0.f, 0.f, 0.f, 0.f};
    z = __builtin_amdgcn_mfma_f32_16x16x32_bf16(aq0, bk0, z, 0, 0, 0);
    z = __builtin_amdgcn_mfma_f32_16x16x32_bf16(aq1, bk1, z, 0, 0, 0);
    sacc[cn] = z;
  }

  // row softmax: lane holds cols cn*16+lr of rows wq0 + lg*4 + jr
  #pragma unroll
  for (int jr = 0; jr < 4; ++jr){
    const int R = wq0 + lg*4 + jr;     // row within 64-block
    float v[8], mx = -1e30f;
    #pragma unroll
    for (int cn = 0; cn < 8; ++cn){
      int c = cn*16 + lr;
      float sc = sacc[cn][jr] * 0.125f + kb[c];
      if (c < R || c > R + 64) sc = -1e30f;   // band mask
      v[cn] = sc;
      mx = fmaxf(mx, sc);
    }
    #pragma unroll
    for (int o = 1; o < 16; o <<= 1) mx = fmaxf(mx, __shfl_xor(mx, o));
    float sum = 0.f;
    #pragma unroll
    for (int cn = 0; cn < 8; ++cn){ v[cn] = __expf(v[cn] - mx); sum += v[cn]; }
    #pragma unroll
    for (int o = 1; o < 16; o <<= 1) sum += __shfl_xor(sum, o);
    float qm = mask[rb + s0 + R];
    float inv = ((qm < 0.999f) ? 0.0f : 1.0f) / sum;
    #pragma unroll
    for (int cn = 0; cn < 8; ++cn)
      P_lds[R][cn*16 + lr] = f2b(v[cn] * inv);
  }
  // P write->read is within-wave (rows wq0..wq0+15); LDS ops are in-order per wave.

  // PV: ctx[16x64 strip] = P[16x128] @ V[128x64]
  short8v ap[4];
  #pragma unroll
  for (int ks = 0; ks < 4; ++ks)
    ap[ks] = *(const short8v*)(&P_lds[wq0 + lr][ks*32 + lk]);
  #pragma unroll
  for (int dn = 0; dn < 4; ++dn){
    f32x4 z = {0.f, 0.f, 0.f, 0.f};
    #pragma unroll
    for (int ks = 0; ks < 4; ++ks){
      short8v bv = *(const short8v*)(&Vt[dn*16 + lr][ks*32 + lk]);
      z = __builtin_amdgcn_mfma_f32_16x16x32_bf16(ap[ks], bv, z, 0, 0, 0);
    }
    #pragma unroll
    for (int jr = 0; jr < 4; ++jr){
      int R = wq0 + lg*4 + jr;
      ctx[(rb + s0 + R)*H_ + hh*64 + dn*16 + lr] = f2b(z[jr]);
    }
  }
}

// ---------------------------------------------------------------- pooling
__global__ __launch_bounds__(256) void pool_logit(const ushort* __restrict__ e,
    const float* __restrict__ w2, const float* __restrict__ b2p,
    const float* __restrict__ mask, float* __restrict__ alpha)
{
  int tid = threadIdx.x, wave = tid >> 6, lane = tid & 63;
  int r = blockIdx.x * 4 + wave;
  short8v ev = *(const short8v*)(e + (size_t)r*H_ + lane*8);
  float sacc = 0.f;
  #pragma unroll
  for (int j = 0; j < 8; ++j) sacc += b2f((ushort)ev[j]) * w2[lane*8 + j];
  #pragma unroll
  for (int o = 32; o > 0; o >>= 1) sacc += __shfl_xor(sacc, o);
  if (lane == 0){
    float logit = sacc + b2p[0];
    alpha[r] = __expf(logit) * mask[r];
  }
}

__global__ __launch_bounds__(256) void pool_sum(const float* __restrict__ alpha,
                                                float* __restrict__ invsum)
{
  __shared__ float red[4];
  int b = blockIdx.x, tid = threadIdx.x, wave = tid >> 6, lane = tid & 63;
  float s = 0.f;
  for (int k = tid; k < S_; k += 256) s += alpha[b*S_ + k];
  #pragma unroll
  for (int o = 32; o > 0; o >>= 1) s += __shfl_xor(s, o);
  if (lane == 0) red[wave] = s;
  __syncthreads();
  if (tid == 0) invsum[b] = 1.0f / (red[0] + red[1] + red[2] + red[3] + 1e-8f);
}

// deterministic chunked weighted sum (float2): outacc[chunk][b][h]
__global__ __launch_bounds__(256) void pool_wsum(const float* __restrict__ x,
    const float* __restrict__ alpha, float* __restrict__ out_acc)
{
  int chunk = blockIdx.x, b = blockIdx.y, tid = threadIdx.x;
  int s0 = chunk * 128;
  int c0 = tid * 2;
  float a0 = 0.f, a1 = 0.f;
  for (int i = 0; i < 128; ++i){
    int srow = s0 + i;
    float al = alpha[b*S_ + srow];
    float2 xv = *(const float2*)(x + (size_t)(b*S_ + srow)*H_ + c0);
    a0 += xv.x * al;
    a1 += xv.y * al;
  }
  float2 o; o.x = a0; o.y = a1;
  *(float2*)(out_acc + (size_t)chunk*B_*H_ + b*H_ + c0) = o;
}

__global__ __launch_bounds__(256) void pool_final(const float* __restrict__ out_acc,
    const float* __restrict__ invsum, float* __restrict__ out)
{
  int i = blockIdx.x * 256 + threadIdx.x;
  if (i < B_*H_){
    int b = i >> 9;
    float s = 0.f;
    #pragma unroll
    for (int c = 0; c < 16; ++c) s += out_acc[(size_t)c*B_*H_ + i];
    out[i] = s * invsum[b];
  }
}

// ---------------------------------------------------------------- launch
extern "C" void kernel_launch(void* const* d_in, const int* in_sizes, int n_in,
                              void* d_out, int out_size, void* d_ws, size_t ws_size,
                              hipStream_t stream)
{
  const float* input_embs = (const float*)d_in[0];
  const float* mask       = (const float*)d_in[1];
  const float* pos        = (const float*)d_in[2];
  const float* ln_emb_g   = (const float*)d_in[3];
  const float* ln_emb_b   = (const float*)d_in[4];
  const float* Wq  = (const float*)d_in[5];
  const float* bq  = (const float*)d_in[6];
  const float* Wk  = (const float*)d_in[7];
  const float* bk  = (const float*)d_in[8];
  const float* Wv  = (const float*)d_in[9];
  const float* bv  = (const float*)d_in[10];
  const float* Wo  = (const float*)d_in[11];
  const float* bo  = (const float*)d_in[12];
  const float* ln1_g = (const float*)d_in[13];
  const float* ln1_b = (const float*)d_in[14];
  const float* Wi  = (const float*)d_in[15];
  const float* bi  = (const float*)d_in[16];
  const float* Wo2 = (const float*)d_in[17];
  const float* bo2 = (const float*)d_in[18];
  const float* ln2_g = (const float*)d_in[19];
  const float* ln2_b = (const float*)d_in[20];
  const float* pW1 = (const float*)d_in[21];
  const float* pb1 = (const float*)d_in[22];
  const float* pW2 = (const float*)d_in[23];
  const float* pb2 = (const float*)d_in[24];

  char* ws = (char*)d_ws;
  size_t off = 0;
  auto alloc = [&](size_t bytes)->char*{
    char* p = ws + off; off += (bytes + 255) & ~(size_t)255; return p;
  };
  ushort* WqkvT  = (ushort*)alloc((size_t)L_*1536*512*2);
  ushort* WoT    = (ushort*)alloc((size_t)L_*512*512*2);
  ushort* WiT    = (ushort*)alloc((size_t)L_*2048*512*2);
  ushort* Wo2T   = (ushort*)alloc((size_t)L_*512*2048*2);
  ushort* pW1T   = (ushort*)alloc((size_t)512*512*2);
  float*  bqkv   = (float*)alloc((size_t)L_*1536*4);
  ushort* h16    = (ushort*)alloc((size_t)M_*H_*2);
  float*  h32    = (float*)alloc((size_t)M_*H_*4);
  ushort* qkv    = (ushort*)alloc((size_t)M_*1536*2);
  ushort* ctx    = (ushort*)alloc((size_t)M_*H_*2);
  ushort* attn16 = (ushort*)alloc((size_t)M_*H_*2);
  float*  attn32 = (float*)alloc((size_t)M_*H_*4);
  ushort* inter  = (ushort*)alloc((size_t)M_*INTER_*2);
  float*  t1     = (float*)alloc((size_t)2*M_*H_*4);   // 2 split-K partials
  float*  alpha  = (float*)alloc((size_t)M_*4);
  float*  invsum = (float*)alloc(256);
  float*  outacc = (float*)alloc((size_t)16*B_*H_*4);

  dim3 tb(256);
  transpose_k<<<dim3(16,16,L_), tb, 0, stream>>>(Wq, WqkvT,            512,  512, (size_t)512*512,  (size_t)1536*512);
  transpose_k<<<dim3(16,16,L_), tb, 0, stream>>>(Wk, WqkvT + 512*512,  512,  512, (size_t)512*512,  (size_t)1536*512);
  transpose_k<<<dim3(16,16,L_), tb, 0, stream>>>(Wv, WqkvT + 1024*512, 512,  512, (size_t)512*512,  (size_t)1536*512);
  transpose_k<<<dim3(16,16,L_), tb, 0, stream>>>(Wo, WoT,              512,  512, (size_t)512*512,  (size_t)512*512);
  transpose_k<<<dim3(64,16,L_), tb, 0, stream>>>(Wi, WiT,              512, 2048, (size_t)512*2048, (size_t)2048*512);
  transpose_k<<<dim3(16,64,L_), tb, 0, stream>>>(Wo2, Wo2T,           2048,  512, (size_t)2048*512, (size_t)512*2048);
  transpose_k<<<dim3(16,16,1),  tb, 0, stream>>>(pW1, pW1T,            512,  512, 0, 0);
  pack_bqkv<<<dim3(L_*1536/256), tb, 0, stream>>>(bq, bk, bv, bqkv);

  embed_ln<<<dim3(M_), tb, 0, stream>>>(input_embs, pos, ln_emb_g, ln_emb_b, h16, h32);

  for (int l = 0; l < L_; ++l){
    gemm_bt<0,128><<<dim3(12,32,1), tb, 0, stream>>>(h16, WqkvT + (size_t)l*1536*512, bqkv + l*1536,
                                                     qkv, nullptr, M_, 1536, 512, 512);
    attn_mfma<<<dim3(S_/64, B_*NH_), tb, 0, stream>>>(qkv, mask, ctx);
    gemm_bt<3,64><<<dim3(4,64,2), tb, 0, stream>>>(ctx, WoT + (size_t)l*512*512, bo + l*512,
                                                   nullptr, t1, M_, 512, 512, 256);
    ln_res<<<dim3(M_), tb, 0, stream>>>(t1, h32, ln1_g + l*512, ln1_b + l*512, attn16, attn32);
    gemm_bt<1,128><<<dim3(16,32,1), tb, 0, stream>>>(attn16, WiT + (size_t)l*2048*512, bi + l*2048,
                                                     inter, nullptr, M_, 2048, 512, 512);
    gemm_bt<3,64><<<dim3(4,64,2), tb, 0, stream>>>(inter, Wo2T + (size_t)l*512*2048, bo2 + l*512,
                                                   nullptr, t1, M_, 512, 2048, 1024);
    ln_res<<<dim3(M_), tb, 0, stream>>>(t1, attn32, ln2_g + l*512, ln2_b + l*512, h16, h32);
  }

  // pooling: e = tanh(h @ pW1 + pb1)  (reuse ctx buffer for e)
  gemm_bt<2,64><<<dim3(4,64,1), tb, 0, stream>>>(h16, pW1T, pb1, ctx, nullptr, M_, 512, 512, 512);
  pool_logit<<<dim3(M_/4), tb, 0, stream>>>(ctx, pW2, pb2, mask, alpha);
  pool_sum<<<dim3(B_), tb, 0, stream>>>(alpha, invsum);
  pool_wsum<<<dim3(16, B_), tb, 0, stream>>>(h32, alpha, outacc);
  pool_final<<<dim3((B_*H_ + 255)/256), tb, 0, stream>>>(outacc, invsum, (float*)d_out);
}

// Round 10
// 403.577 us; speedup vs baseline: 1.1776x; 1.0183x over previous
//
#include <hip/hip_runtime.h>
#include <hip/hip_bf16.h>
#include <math.h>

#define B_ 2
#define S_ 2048
#define H_ 512
#define NH_ 8
#define HD_ 64
#define L_ 4
#define INTER_ 2048
#define W1_ 32
#define WB_ 65
#define M_ (B_*S_)   // 4096

typedef __attribute__((ext_vector_type(8))) short short8v;
typedef __attribute__((ext_vector_type(4))) float f32x4;

__device__ __forceinline__ float b2f(ushort u){ return __uint_as_float(((unsigned)u)<<16); }
__device__ __forceinline__ ushort f2b(float f){
  unsigned u = __float_as_uint(f);
  unsigned r = (u + 0x7fffu + ((u>>16)&1u)) >> 16;
  return (ushort)r;
}

// async global->LDS, 16B per lane (linear LDS dest = base + lane*16).
__device__ __forceinline__ void async16(const ushort* g, ushort* l){
  __builtin_amdgcn_global_load_lds(
      (const __attribute__((address_space(1))) unsigned int*)g,
      (__attribute__((address_space(3))) unsigned int*)l, 16, 0, 0);
}

// ---------------------------------------------------------------- transposes
// generic tile body: src [R][C] f32 -> dst [C][R] bf16
__device__ __forceinline__ void tr_tile(const float* __restrict__ src,
    ushort* __restrict__ dst, int R, int C, int r0, int c0)
{
  __shared__ ushort tile[32][33];
  int tx = threadIdx.x & 31, ty = threadIdx.x >> 5;   // 32 x 8
  #pragma unroll
  for (int i = 0; i < 4; ++i){
    int r = r0 + ty + i*8;
    tile[ty + i*8][tx] = f2b(src[(size_t)r * C + c0 + tx]);
  }
  __syncthreads();
  #pragma unroll
  for (int i = 0; i < 4; ++i){
    int c = c0 + ty + i*8;
    dst[(size_t)c * R + r0 + tx] = tile[tx][ty + i*8];
  }
}

struct TPack {
  const float* wq; const float* wk; const float* wv;
  const float* wo; const float* pw1;
  ushort* wqkvT; ushort* woT; ushort* pw1T;
};

// all 512x512 weights in one dispatch: z = 0..11 QKV, 12..15 Wo, 16 pW1
__global__ __launch_bounds__(256) void transpose512_all(TPack p)
{
  int z = blockIdx.z;
  const float* src; ushort* dst;
  if (z < 12){
    int kind = z >> 2, l = z & 3;
    const float* s3[3] = {p.wq, p.wk, p.wv};
    src = s3[kind] + (size_t)l*512*512;
    dst = p.wqkvT + (size_t)l*1536*512 + (size_t)kind*512*512;
  } else if (z < 16){
    int l = z - 12;
    src = p.wo + (size_t)l*512*512;
    dst = p.woT + (size_t)l*512*512;
  } else {
    src = p.pw1; dst = p.pw1T;
  }
  tr_tile(src, dst, 512, 512, blockIdx.y*32, blockIdx.x*32);
}

__global__ __launch_bounds__(256) void transpose_k(const float* __restrict__ src,
    ushort* __restrict__ dst, int R, int C, size_t sBatch, size_t dBatch)
{
  src += (size_t)blockIdx.z * sBatch;
  dst += (size_t)blockIdx.z * dBatch;
  tr_tile(src, dst, R, C, blockIdx.y*32, blockIdx.x*32);
}

__global__ __launch_bounds__(256) void pack_bqkv(const float* __restrict__ bq,
    const float* __restrict__ bk, const float* __restrict__ bv, float* __restrict__ dst)
{
  int i = blockIdx.x * 256 + threadIdx.x;      // < L_*1536
  int l = i / 1536, n = i % 1536;
  float v = (n < 512) ? bq[l*512 + n] : (n < 1024 ? bk[l*512 + n - 512] : bv[l*512 + n - 1024]);
  dst[i] = v;
}

// ---------------------------------------------------------------- GEMM (B^T)
// C[M,N] = A[M,K(part)] @ Bt[N,K]^T (+ bias on z==0)
// EPI: 0=bf16, 1=gelu->bf16, 2=tanh->bf16, 3=f32 (split-K partial at z*M*N)
// BM x 128 tile (BM = 64 or 128), BK=32; 4 waves; 3-buffer counted-vmcnt
// pipeline; XOR-swizzled LDS (inverse-swizzled global source, swizzled reads).
template<int EPI, int BM>
__global__ __launch_bounds__(256, (BM == 64) ? 4 : 3) void gemm_bt(
    const ushort* __restrict__ A, const ushort* __restrict__ Bt,
    const float* __restrict__ bias, ushort* __restrict__ o16,
    float* __restrict__ o32, int M, int N, int K, int Klen)
{
  constexpr int ABUF = BM * 32;          // elems per A tile
  constexpr int BUFE = ABUF + 4096;      // + B tile (128x32)
  constexpr int MI = BM / 32;            // acc rows per wave
  constexpr int AL = BM / 64;            // A staging rounds per tile
  __shared__ ushort lds[3 * BUFE];
  const int tid = threadIdx.x;
  const int bm = blockIdx.y * BM, bn = blockIdx.x * 128;
  const int kbeg = blockIdx.z * Klen;
  const int wave = tid >> 6, lane = tid & 63;
  const int wr = (wave >> 1) * (BM / 2), wc = (wave & 1) * 64;
  const int lr = lane & 15, lg = lane >> 4;
  const int lkS = (lg ^ ((lr >> 1) & 3)) * 8;      // swizzled read chunk (lane-const)
  f32x4 acc[MI][4] = {};

  // staging: thread t -> row t>>2; SOURCE chunk is inverse-swizzled so that
  // linear DMA dest + swizzled read = identity (both-sides-or-neither).
  const int srow = tid >> 2;
  const int schk = (((tid & 3) ^ ((tid >> 3) & 3))) * 8;
  const ushort* Ag  = A  + (size_t)(bm + srow) * K + kbeg + schk;
  const ushort* Bg0 = Bt + (size_t)(bn + srow) * K + kbeg + schk;
  const ushort* Bg1 = Bt + (size_t)(bn + 64 + srow) * K + kbeg + schk;

  const int nIter = Klen >> 5;
  auto issueTile = [&](int t, int buf){
    int k0 = t << 5;
    ushort* d = &lds[0] + buf*BUFE + tid*8;
    #pragma unroll
    for (int r = 0; r < AL; ++r)
      async16(Ag + (size_t)r*64*K + k0, d + r*2048);
    async16(Bg0 + k0, d + ABUF);
    async16(Bg1 + k0, d + ABUF + 2048);
  };

  // prologue: tiles 0 and 1 in flight
  issueTile(0, 0);
  issueTile(1, 1);

  int cb = 0;                           // buffer holding tile t
  for (int t = 0; t < nIter; ++t){
    int ib = cb + 2; if (ib >= 3) ib -= 3;
    if (t + 2 < nIter) issueTile(t + 2, ib);
    if constexpr (BM == 64){
      if (t + 2 < nIter)      asm volatile("s_waitcnt vmcnt(6)" ::: "memory");
      else if (t + 1 < nIter) asm volatile("s_waitcnt vmcnt(3)" ::: "memory");
      else                    asm volatile("s_waitcnt vmcnt(0)" ::: "memory");
    } else {
      if (t + 2 < nIter)      asm volatile("s_waitcnt vmcnt(8)" ::: "memory");
      else if (t + 1 < nIter) asm volatile("s_waitcnt vmcnt(4)" ::: "memory");
      else                    asm volatile("s_waitcnt vmcnt(0)" ::: "memory");
    }
    __builtin_amdgcn_sched_barrier(0);
    __builtin_amdgcn_s_barrier();       // tile t visible to all waves
    const ushort* bufp = &lds[0] + cb*BUFE;
    short8v af[MI], bfr[4];
    #pragma unroll
    for (int mi = 0; mi < MI; ++mi)
      af[mi] = *(const short8v*)(bufp + (wr + mi*16 + lr)*32 + lkS);
    #pragma unroll
    for (int nj = 0; nj < 4; ++nj)
      bfr[nj] = *(const short8v*)(bufp + ABUF + (wc + nj*16 + lr)*32 + lkS);
    #pragma unroll
    for (int mi = 0; mi < MI; ++mi)
      #pragma unroll
      for (int nj = 0; nj < 4; ++nj)
        acc[mi][nj] = __builtin_amdgcn_mfma_f32_16x16x32_bf16(af[mi], bfr[nj], acc[mi][nj], 0, 0, 0);
    __builtin_amdgcn_s_barrier();       // all reads of buf cb done before reuse
    cb = cb + 1; if (cb == 3) cb = 0;
  }

  const float bscale = (blockIdx.z == 0) ? 1.0f : 0.0f;
  #pragma unroll
  for (int mi = 0; mi < MI; ++mi){
    #pragma unroll
    for (int nj = 0; nj < 4; ++nj){
      int col = bn + wc + nj*16 + lr;
      float bv = bias[col] * bscale;
      #pragma unroll
      for (int j = 0; j < 4; ++j){
        int row = bm + wr + mi*16 + lg*4 + j;
        float v = acc[mi][nj][j] + bv;
        if (EPI == 1) v = 0.5f * v * (1.0f + erff(v * 0.70710678118654752f));
        if (EPI == 2) v = tanhf(v);
        if (EPI == 3) o32[(size_t)blockIdx.z*M*N + (size_t)row * N + col] = v;
        else          o16[(size_t)row * N + col] = f2b(v);
      }
    }
  }
}

// ---------------------------------------------------------------- LayerNorm
__device__ __forceinline__ void block_ln_stats(float v0, float v1, float* red,
                                               float& mean, float& rstd)
{
  int tid = threadIdx.x, wave = tid >> 6, lane = tid & 63;
  float sm = v0 + v1;
  float sq = v0*v0 + v1*v1;
  #pragma unroll
  for (int o = 32; o > 0; o >>= 1){ sm += __shfl_xor(sm, o); sq += __shfl_xor(sq, o); }
  if (lane == 0){ red[wave] = sm; red[4 + wave] = sq; }
  __syncthreads();
  float S = red[0] + red[1] + red[2] + red[3];
  float Q = red[4] + red[5] + red[6] + red[7];
  mean = S * (1.0f / 512.0f);
  float var = Q * (1.0f / 512.0f) - mean*mean;
  if (var < 0.f) var = 0.f;
  rstd = rsqrtf(var + 1e-12f);
}

// embeddings LN (float2 vectorized): x,pos f32 -> out bf16 + f32 shadow
__global__ __launch_bounds__(256) void embed_ln(const float* __restrict__ x,
    const float* __restrict__ pos, const float* __restrict__ g,
    const float* __restrict__ bb, ushort* __restrict__ out16, float* __restrict__ out32)
{
  __shared__ float red[8];
  int row = blockIdx.x, tid = threadIdx.x;
  int s = row & (S_ - 1);
  const size_t base = (size_t)row*H_ + tid*2;
  float2 xv = *(const float2*)(x + base);
  float2 pv = *(const float2*)(pos + (size_t)s*H_ + tid*2);
  float v0 = xv.x + pv.x, v1 = xv.y + pv.y;
  float mean, rstd;
  block_ln_stats(v0, v1, red, mean, rstd);
  float2 gv = *(const float2*)(g + tid*2);
  float2 bv = *(const float2*)(bb + tid*2);
  float r0 = (v0 - mean)*rstd*gv.x + bv.x;
  float r1 = (v1 - mean)*rstd*gv.y + bv.y;
  ushort2 o2; o2.x = f2b(r0); o2.y = f2b(r1);
  *(ushort2*)(out16 + base) = o2;
  float2 f2v; f2v.x = r0; f2v.y = r1;
  *(float2*)(out32 + base) = f2v;
}

// LN(t0 + t1 + res32) float2 vectorized
__global__ __launch_bounds__(256) void ln_res(const float* __restrict__ t,
    const float* __restrict__ res, const float* __restrict__ g,
    const float* __restrict__ bb, ushort* __restrict__ out16, float* __restrict__ out32)
{
  __shared__ float red[8];
  int row = blockIdx.x, tid = threadIdx.x;
  const size_t MN = (size_t)M_*H_;
  const size_t base = (size_t)row*H_ + tid*2;
  float2 t0 = *(const float2*)(t + base);
  float2 t1v = *(const float2*)(t + MN + base);
  float2 rv = *(const float2*)(res + base);
  float v0 = t0.x + t1v.x + rv.x;
  float v1 = t0.y + t1v.y + rv.y;
  float mean, rstd;
  block_ln_stats(v0, v1, red, mean, rstd);
  float2 gv = *(const float2*)(g + tid*2);
  float2 bv = *(const float2*)(bb + tid*2);
  float r0 = (v0 - mean)*rstd*gv.x + bv.x;
  float r1 = (v1 - mean)*rstd*gv.y + bv.y;
  ushort2 o2; o2.x = f2b(r0); o2.y = f2b(r1);
  *(ushort2*)(out16 + base) = o2;
  float2 f2v; f2v.x = r0; f2v.y = r1;
  *(float2*)(out32 + base) = f2v;
}

// ---------------------------------------------------------------- attention (MFMA)
// qkv: [B*S][1536] bf16 (q|k|v each 512). Block: 256 thr (4 waves) = one
// (b,h) x 64-row Q-block. Keys/values: 128-wide chunk [s0-32, s0+95].
__global__ __launch_bounds__(256) void attn_mfma(const ushort* __restrict__ qkv,
    const float* __restrict__ mask, ushort* __restrict__ ctx)
{
  __shared__ ushort K_lds[128][72];   // [key c][k]   (pad 72: 2-way free)
  __shared__ ushort Vt[64][136];      // [d][key c]   (pad 136)
  __shared__ ushort P_lds[64][136];   // [q row][key c]
  __shared__ float  kb[128];

  const int tid = threadIdx.x, wave = tid >> 6, lane = tid & 63;
  const int hh = blockIdx.y & (NH_ - 1), b = blockIdx.y >> 3;
  const int s0 = blockIdx.x * 64;
  const size_t rb = (size_t)b * S_;

  // ---- stage K rows c=0..127 and V^T (2 keys/thread, ushort2 transposed writes)
  const int ch = tid & 7;             // 16B chunk within 64-d row
  const int rr = tid >> 3;            // 0..31
  #pragma unroll
  for (int it = 0; it < 2; ++it){
    int c0 = rr*2 + it*64;
    short8v vv[2];
    #pragma unroll
    for (int p = 0; p < 2; ++p){
      int c = c0 + p;
      int j = s0 - 32 + c;
      int jc = min(max(j, 0), S_ - 1);
      const size_t rowb = (rb + jc) * 1536 + hh*64 + ch*8;
      *(short8v*)(&K_lds[c][ch*8]) = *(const short8v*)(qkv + rowb + 512);
      vv[p] = *(const short8v*)(qkv + rowb + 1024);
    }
    #pragma unroll
    for (int t = 0; t < 8; ++t){      // staggered transposed ushort2 writes
      int tt = (t + ch) & 7;
      int d = ch*8 + tt;
      ushort2 w; w.x = (ushort)vv[0][tt]; w.y = (ushort)vv[1][tt];
      *(ushort2*)(&Vt[d][c0]) = w;
    }
  }
  if (tid < 128){
    int j = s0 - 32 + tid;
    kb[tid] = (j >= 0 && j < S_) ? (1.0f - mask[rb + j]) * (-10000.0f) : -1e30f;
  }
  __syncthreads();

  const int wq0 = wave * 16;
  const int lr = lane & 15, lg = lane >> 4, lk = lg * 8;

  // Q fragments (A): row = wq0+lr, k = lk..lk+7 (+32 for second frag)
  const ushort* qbase = qkv + (rb + s0 + wq0 + lr) * 1536 + hh*64;
  short8v aq0 = *(const short8v*)(qbase + lk);
  short8v aq1 = *(const short8v*)(qbase + 32 + lk);

  // scores: 16x128 strip per wave
  f32x4 sacc[8];
  #pragma unroll
  for (int cn = 0; cn < 8; ++cn){
    short8v bk0 = *(const short8v*)(&K_lds[cn*16 + lr][lk]);
    short8v bk1 = *(const short8v*)(&K_lds[cn*16 + lr][32 + lk]);
    f32x4 z = {0.f, 0.f, 0.f, 0.f};
    z = __builtin_amdgcn_mfma_f32_16x16x32_bf16(aq0, bk0, z, 0, 0, 0);
    z = __builtin_amdgcn_mfma_f32_16x16x32_bf16(aq1, bk1, z, 0, 0, 0);
    sacc[cn] = z;
  }

  // row softmax: lane holds cols cn*16+lr of rows wq0 + lg*4 + jr
  #pragma unroll
  for (int jr = 0; jr < 4; ++jr){
    const int R = wq0 + lg*4 + jr;     // row within 64-block
    float v[8], mx = -1e30f;
    #pragma unroll
    for (int cn = 0; cn < 8; ++cn){
      int c = cn*16 + lr;
      float sc = sacc[cn][jr] * 0.125f + kb[c];
      if (c < R || c > R + 64) sc = -1e30f;   // band mask
      v[cn] = sc;
      mx = fmaxf(mx, sc);
    }
    #pragma unroll
    for (int o = 1; o < 16; o <<= 1) mx = fmaxf(mx, __shfl_xor(mx, o));
    float sum = 0.f;
    #pragma unroll
    for (int cn = 0; cn < 8; ++cn){ v[cn] = __expf(v[cn] - mx); sum += v[cn]; }
    #pragma unroll
    for (int o = 1; o < 16; o <<= 1) sum += __shfl_xor(sum, o);
    float qm = mask[rb + s0 + R];
    float inv = ((qm < 0.999f) ? 0.0f : 1.0f) / sum;
    #pragma unroll
    for (int cn = 0; cn < 8; ++cn)
      P_lds[R][cn*16 + lr] = f2b(v[cn] * inv);
  }
  // P write->read is within-wave (rows wq0..wq0+15); LDS ops are in-order per wave.

  // PV: ctx[16x64 strip] = P[16x128] @ V[128x64]
  short8v ap[4];
  #pragma unroll
  for (int ks = 0; ks < 4; ++ks)
    ap[ks] = *(const short8v*)(&P_lds[wq0 + lr][ks*32 + lk]);
  #pragma unroll
  for (int dn = 0; dn < 4; ++dn){
    f32x4 z = {0.f, 0.f, 0.f, 0.f};
    #pragma unroll
    for (int ks = 0; ks < 4; ++ks){
      short8v bv = *(const short8v*)(&Vt[dn*16 + lr][ks*32 + lk]);
      z = __builtin_amdgcn_mfma_f32_16x16x32_bf16(ap[ks], bv, z, 0, 0, 0);
    }
    #pragma unroll
    for (int jr = 0; jr < 4; ++jr){
      int R = wq0 + lg*4 + jr;
      ctx[(rb + s0 + R)*H_ + hh*64 + dn*16 + lr] = f2b(z[jr]);
    }
  }
}

// ---------------------------------------------------------------- pooling
__global__ __launch_bounds__(256) void pool_logit(const ushort* __restrict__ e,
    const float* __restrict__ w2, const float* __restrict__ b2p,
    const float* __restrict__ mask, float* __restrict__ alpha)
{
  int tid = threadIdx.x, wave = tid >> 6, lane = tid & 63;
  int r = blockIdx.x * 4 + wave;
  short8v ev = *(const short8v*)(e + (size_t)r*H_ + lane*8);
  float sacc = 0.f;
  #pragma unroll
  for (int j = 0; j < 8; ++j) sacc += b2f((ushort)ev[j]) * w2[lane*8 + j];
  #pragma unroll
  for (int o = 32; o > 0; o >>= 1) sacc += __shfl_xor(sacc, o);
  if (lane == 0){
    float logit = sacc + b2p[0];
    alpha[r] = __expf(logit) * mask[r];
  }
}

__global__ __launch_bounds__(256) void pool_sum(const float* __restrict__ alpha,
                                                float* __restrict__ invsum)
{
  __shared__ float red[4];
  int b = blockIdx.x, tid = threadIdx.x, wave = tid >> 6, lane = tid & 63;
  float s = 0.f;
  for (int k = tid; k < S_; k += 256) s += alpha[b*S_ + k];
  #pragma unroll
  for (int o = 32; o > 0; o >>= 1) s += __shfl_xor(s, o);
  if (lane == 0) red[wave] = s;
  __syncthreads();
  if (tid == 0) invsum[b] = 1.0f / (red[0] + red[1] + red[2] + red[3] + 1e-8f);
}

// deterministic chunked weighted sum (float2): outacc[chunk][b][h]
__global__ __launch_bounds__(256) void pool_wsum(const float* __restrict__ x,
    const float* __restrict__ alpha, float* __restrict__ out_acc)
{
  int chunk = blockIdx.x, b = blockIdx.y, tid = threadIdx.x;
  int s0 = chunk * 128;
  int c0 = tid * 2;
  float a0 = 0.f, a1 = 0.f;
  for (int i = 0; i < 128; ++i){
    int srow = s0 + i;
    float al = alpha[b*S_ + srow];
    float2 xv = *(const float2*)(x + (size_t)(b*S_ + srow)*H_ + c0);
    a0 += xv.x * al;
    a1 += xv.y * al;
  }
  float2 o; o.x = a0; o.y = a1;
  *(float2*)(out_acc + (size_t)chunk*B_*H_ + b*H_ + c0) = o;
}

__global__ __launch_bounds__(256) void pool_final(const float* __restrict__ out_acc,
    const float* __restrict__ invsum, float* __restrict__ out)
{
  int i = blockIdx.x * 256 + threadIdx.x;
  if (i < B_*H_){
    int b = i >> 9;
    float s = 0.f;
    #pragma unroll
    for (int c = 0; c < 16; ++c) s += out_acc[(size_t)c*B_*H_ + i];
    out[i] = s * invsum[b];
  }
}

// ---------------------------------------------------------------- launch
extern "C" void kernel_launch(void* const* d_in, const int* in_sizes, int n_in,
                              void* d_out, int out_size, void* d_ws, size_t ws_size,
                              hipStream_t stream)
{
  const float* input_embs = (const float*)d_in[0];
  const float* mask       = (const float*)d_in[1];
  const float* pos        = (const float*)d_in[2];
  const float* ln_emb_g   = (const float*)d_in[3];
  const float* ln_emb_b   = (const float*)d_in[4];
  const float* Wq  = (const float*)d_in[5];
  const float* bq  = (const float*)d_in[6];
  const float* Wk  = (const float*)d_in[7];
  const float* bk  = (const float*)d_in[8];
  const float* Wv  = (const float*)d_in[9];
  const float* bv  = (const float*)d_in[10];
  const float* Wo  = (const float*)d_in[11];
  const float* bo  = (const float*)d_in[12];
  const float* ln1_g = (const float*)d_in[13];
  const float* ln1_b = (const float*)d_in[14];
  const float* Wi  = (const float*)d_in[15];
  const float* bi  = (const float*)d_in[16];
  const float* Wo2 = (const float*)d_in[17];
  const float* bo2 = (const float*)d_in[18];
  const float* ln2_g = (const float*)d_in[19];
  const float* ln2_b = (const float*)d_in[20];
  const float* pW1 = (const float*)d_in[21];
  const float* pb1 = (const float*)d_in[22];
  const float* pW2 = (const float*)d_in[23];
  const float* pb2 = (const float*)d_in[24];

  char* ws = (char*)d_ws;
  size_t off = 0;
  auto alloc = [&](size_t bytes)->char*{
    char* p = ws + off; off += (bytes + 255) & ~(size_t)255; return p;
  };
  ushort* WqkvT  = (ushort*)alloc((size_t)L_*1536*512*2);
  ushort* WoT    = (ushort*)alloc((size_t)L_*512*512*2);
  ushort* WiT    = (ushort*)alloc((size_t)L_*2048*512*2);
  ushort* Wo2T   = (ushort*)alloc((size_t)L_*512*2048*2);
  ushort* pW1T   = (ushort*)alloc((size_t)512*512*2);
  float*  bqkv   = (float*)alloc((size_t)L_*1536*4);
  ushort* h16    = (ushort*)alloc((size_t)M_*H_*2);
  float*  h32    = (float*)alloc((size_t)M_*H_*4);
  ushort* qkv    = (ushort*)alloc((size_t)M_*1536*2);
  ushort* ctx    = (ushort*)alloc((size_t)M_*H_*2);
  ushort* attn16 = (ushort*)alloc((size_t)M_*H_*2);
  float*  attn32 = (float*)alloc((size_t)M_*H_*4);
  ushort* inter  = (ushort*)alloc((size_t)M_*INTER_*2);
  float*  t1     = (float*)alloc((size_t)2*M_*H_*4);   // 2 split-K partials
  float*  alpha  = (float*)alloc((size_t)M_*4);
  float*  invsum = (float*)alloc(256);
  float*  outacc = (float*)alloc((size_t)16*B_*H_*4);

  dim3 tb(256);
  TPack tp;
  tp.wq = Wq; tp.wk = Wk; tp.wv = Wv; tp.wo = Wo; tp.pw1 = pW1;
  tp.wqkvT = WqkvT; tp.woT = WoT; tp.pw1T = pW1T;
  transpose512_all<<<dim3(16,16,17), tb, 0, stream>>>(tp);
  transpose_k<<<dim3(64,16,L_), tb, 0, stream>>>(Wi, WiT,    512, 2048, (size_t)512*2048, (size_t)2048*512);
  transpose_k<<<dim3(16,64,L_), tb, 0, stream>>>(Wo2, Wo2T, 2048,  512, (size_t)2048*512, (size_t)512*2048);
  pack_bqkv<<<dim3(L_*1536/256), tb, 0, stream>>>(bq, bk, bv, bqkv);

  embed_ln<<<dim3(M_), tb, 0, stream>>>(input_embs, pos, ln_emb_g, ln_emb_b, h16, h32);

  for (int l = 0; l < L_; ++l){
    gemm_bt<0,64><<<dim3(12,64,1), tb, 0, stream>>>(h16, WqkvT + (size_t)l*1536*512, bqkv + l*1536,
                                                    qkv, nullptr, M_, 1536, 512, 512);
    attn_mfma<<<dim3(S_/64, B_*NH_), tb, 0, stream>>>(qkv, mask, ctx);
    gemm_bt<3,64><<<dim3(4,64,2), tb, 0, stream>>>(ctx, WoT + (size_t)l*512*512, bo + l*512,
                                                   nullptr, t1, M_, 512, 512, 256);
    ln_res<<<dim3(M_), tb, 0, stream>>>(t1, h32, ln1_g + l*512, ln1_b + l*512, attn16, attn32);
    gemm_bt<1,128><<<dim3(16,32,1), tb, 0, stream>>>(attn16, WiT + (size_t)l*2048*512, bi + l*2048,
                                                     inter, nullptr, M_, 2048, 512, 512);
    gemm_bt<3,64><<<dim3(4,64,2), tb, 0, stream>>>(inter, Wo2T + (size_t)l*512*2048, bo2 + l*512,
                                                   nullptr, t1, M_, 512, 2048, 1024);
    ln_res<<<dim3(M_), tb, 0, stream>>>(t1, attn32, ln2_g + l*512, ln2_b + l*512, h16, h32);
  }

  // pooling: e = tanh(h @ pW1 + pb1)  (reuse ctx buffer for e)
  gemm_bt<2,64><<<dim3(4,64,1), tb, 0, stream>>>(h16, pW1T, pb1, ctx, nullptr, M_, 512, 512, 512);
  pool_logit<<<dim3(M_/4), tb, 0, stream>>>(ctx, pW2, pb2, mask, alpha);
  pool_sum<<<dim3(B_), tb, 0, stream>>>(alpha, invsum);
  pool_wsum<<<dim3(16, B_), tb, 0, stream>>>(h32, alpha, outacc);
  pool_final<<<dim3((B_*H_ + 255)/256), tb, 0, stream>>>(outacc, invsum, (float*)d_out);
}

// Round 11
// 402.299 us; speedup vs baseline: 1.1813x; 1.0032x over previous
//
#include <hip/hip_runtime.h>
#include <hip/hip_bf16.h>
#include <math.h>

#define B_ 2
#define S_ 2048
#define H_ 512
#define NH_ 8
#define HD_ 64
#define L_ 4
#define INTER_ 2048
#define W1_ 32
#define WB_ 65
#define M_ (B_*S_)   // 4096

typedef __attribute__((ext_vector_type(8))) short short8v;
typedef __attribute__((ext_vector_type(4))) float f32x4;

__device__ __forceinline__ float b2f(ushort u){ return __uint_as_float(((unsigned)u)<<16); }
__device__ __forceinline__ ushort f2b(float f){
  unsigned u = __float_as_uint(f);
  unsigned r = (u + 0x7fffu + ((u>>16)&1u)) >> 16;
  return (ushort)r;
}

// async global->LDS, 16B per lane (linear LDS dest = base + lane*16).
__device__ __forceinline__ void async16(const ushort* g, ushort* l){
  __builtin_amdgcn_global_load_lds(
      (const __attribute__((address_space(1))) unsigned int*)g,
      (__attribute__((address_space(3))) unsigned int*)l, 16, 0, 0);
}

// ---------------------------------------------------------------- transposes
// generic tile body: src [R][C] f32 -> dst [C][R] bf16
__device__ __forceinline__ void tr_tile(const float* __restrict__ src,
    ushort* __restrict__ dst, int R, int C, int r0, int c0)
{
  __shared__ ushort tile[32][33];
  int tx = threadIdx.x & 31, ty = threadIdx.x >> 5;   // 32 x 8
  #pragma unroll
  for (int i = 0; i < 4; ++i){
    int r = r0 + ty + i*8;
    tile[ty + i*8][tx] = f2b(src[(size_t)r * C + c0 + tx]);
  }
  __syncthreads();
  #pragma unroll
  for (int i = 0; i < 4; ++i){
    int c = c0 + ty + i*8;
    dst[(size_t)c * R + r0 + tx] = tile[tx][ty + i*8];
  }
}

struct TPack {
  const float* wq; const float* wk; const float* wv;
  const float* wo; const float* pw1;
  ushort* wqkvT; ushort* woT; ushort* pw1T;
};

// all 512x512 weights in one dispatch: z = 0..11 QKV, 12..15 Wo, 16 pW1
__global__ __launch_bounds__(256) void transpose512_all(TPack p)
{
  int z = blockIdx.z;
  const float* src; ushort* dst;
  if (z < 12){
    int kind = z >> 2, l = z & 3;
    const float* s3[3] = {p.wq, p.wk, p.wv};
    src = s3[kind] + (size_t)l*512*512;
    dst = p.wqkvT + (size_t)l*1536*512 + (size_t)kind*512*512;
  } else if (z < 16){
    int l = z - 12;
    src = p.wo + (size_t)l*512*512;
    dst = p.woT + (size_t)l*512*512;
  } else {
    src = p.pw1; dst = p.pw1T;
  }
  tr_tile(src, dst, 512, 512, blockIdx.y*32, blockIdx.x*32);
}

__global__ __launch_bounds__(256) void transpose_k(const float* __restrict__ src,
    ushort* __restrict__ dst, int R, int C, size_t sBatch, size_t dBatch)
{
  src += (size_t)blockIdx.z * sBatch;
  dst += (size_t)blockIdx.z * dBatch;
  tr_tile(src, dst, R, C, blockIdx.y*32, blockIdx.x*32);
}

__global__ __launch_bounds__(256) void pack_bqkv(const float* __restrict__ bq,
    const float* __restrict__ bk, const float* __restrict__ bv, float* __restrict__ dst)
{
  int i = blockIdx.x * 256 + threadIdx.x;      // < L_*1536
  int l = i / 1536, n = i % 1536;
  float v = (n < 512) ? bq[l*512 + n] : (n < 1024 ? bk[l*512 + n - 512] : bv[l*512 + n - 1024]);
  dst[i] = v;
}

// ---------------------------------------------------------------- GEMM (B^T)
// C[M,N] = A[M,K(part)] @ Bt[N,K]^T (+ bias on z==0)
// EPI: 0=bf16, 1=gelu->bf16, 2=tanh->bf16, 3=f32 (split-K partial at z*M*N)
// BM x 128 tile, BK=64; 4 waves; 2-buffer issue-early pipeline, ONE barrier
// per K-step (m248 2ph recipe); XOR-swizzled LDS (granule ^ (row&7), applied
// to BOTH the staged global source and the read side).
template<int EPI, int BM>
__global__ __launch_bounds__(256, (BM == 64) ? 3 : 2) void gemm_bt(
    const ushort* __restrict__ A, const ushort* __restrict__ Bt,
    const float* __restrict__ bias, ushort* __restrict__ o16,
    float* __restrict__ o32, int M, int N, int K, int Klen)
{
  constexpr int ABUF = BM * 64;            // elems per A tile
  constexpr int BUFE = ABUF + 128 * 64;    // + B tile
  constexpr int MI = BM / 32;              // acc rows per wave
  constexpr int AR = (BM * 8) / 256;       // A staging rounds (16B granules)
  constexpr int BR = 4;                    // B staging rounds
  __shared__ ushort lds[2 * BUFE];
  const int tid = threadIdx.x;
  const int bm = blockIdx.y * BM, bn = blockIdx.x * 128;
  const int kbeg = blockIdx.z * Klen;
  const int wave = tid >> 6, lane = tid & 63;
  const int wr = (wave >> 1) * (BM / 2), wc = (wave & 1) * 64;
  const int lr = lane & 15, lg = lane >> 4;
  const int l7 = lr & 7;
  f32x4 acc[MI][4] = {};

  // staging sources, swizzled granule: LDS slot (r,g) holds global chunk g^(r&7)
  const ushort* srcA[AR];
  const ushort* srcB[BR];
  #pragma unroll
  for (int ra = 0; ra < AR; ++ra){
    int s = tid + ra*256; int r = s >> 3, g = s & 7;
    srcA[ra] = A + (size_t)(bm + r) * K + kbeg + (g ^ (r & 7)) * 8;
  }
  #pragma unroll
  for (int rb = 0; rb < BR; ++rb){
    int s = tid + rb*256; int r = s >> 3, g = s & 7;
    srcB[rb] = Bt + (size_t)(bn + r) * K + kbeg + (g ^ (r & 7)) * 8;
  }

  const int nIter = Klen >> 6;
  auto issueTile = [&](int t, int buf){
    int k0 = t << 6;
    ushort* dA = &lds[0] + buf*BUFE + tid*8;
    ushort* dB = &lds[0] + buf*BUFE + ABUF + tid*8;
    #pragma unroll
    for (int ra = 0; ra < AR; ++ra) async16(srcA[ra] + k0, dA + ra*2048);
    #pragma unroll
    for (int rb = 0; rb < BR; ++rb) async16(srcB[rb] + k0, dB + rb*2048);
  };

  // prologue: tile 0 staged and visible
  issueTile(0, 0);
  asm volatile("s_waitcnt vmcnt(0)" ::: "memory");
  __builtin_amdgcn_s_barrier();

  int cur = 0;
  for (int t = 0; t < nIter; ++t){
    if (t + 1 < nIter) issueTile(t + 1, cur ^ 1);  // overlaps compute below
    const ushort* bufp = &lds[0] + cur*BUFE;
    #pragma unroll
    for (int ks = 0; ks < 2; ++ks){
      short8v af[MI], bfr[4];
      #pragma unroll
      for (int mi = 0; mi < MI; ++mi){
        int R = wr + mi*16 + lr;
        af[mi] = *(const short8v*)(bufp + R*64 + (((ks*4 + lg) ^ l7) * 8));
      }
      #pragma unroll
      for (int nj = 0; nj < 4; ++nj){
        int Rb = wc + nj*16 + lr;
        bfr[nj] = *(const short8v*)(bufp + ABUF + Rb*64 + (((ks*4 + lg) ^ l7) * 8));
      }
      #pragma unroll
      for (int mi = 0; mi < MI; ++mi)
        #pragma unroll
        for (int nj = 0; nj < 4; ++nj)
          acc[mi][nj] = __builtin_amdgcn_mfma_f32_16x16x32_bf16(af[mi], bfr[nj], acc[mi][nj], 0, 0, 0);
    }
    asm volatile("s_waitcnt vmcnt(0)" ::: "memory");  // t+1 loads done (remainder)
    __builtin_amdgcn_s_barrier();                      // all reads of cur finished
    cur ^= 1;
  }

  const float bscale = (blockIdx.z == 0) ? 1.0f : 0.0f;
  #pragma unroll
  for (int mi = 0; mi < MI; ++mi){
    #pragma unroll
    for (int nj = 0; nj < 4; ++nj){
      int col = bn + wc + nj*16 + lr;
      float bv = bias[col] * bscale;
      #pragma unroll
      for (int j = 0; j < 4; ++j){
        int row = bm + wr + mi*16 + lg*4 + j;
        float v = acc[mi][nj][j] + bv;
        if (EPI == 1) v = 0.5f * v * (1.0f + erff(v * 0.70710678118654752f));
        if (EPI == 2) v = tanhf(v);
        if (EPI == 3) o32[(size_t)blockIdx.z*M*N + (size_t)row * N + col] = v;
        else          o16[(size_t)row * N + col] = f2b(v);
      }
    }
  }
}

// ---------------------------------------------------------------- LayerNorm
__device__ __forceinline__ void block_ln_stats(float v0, float v1, float* red,
                                               float& mean, float& rstd)
{
  int tid = threadIdx.x, wave = tid >> 6, lane = tid & 63;
  float sm = v0 + v1;
  float sq = v0*v0 + v1*v1;
  #pragma unroll
  for (int o = 32; o > 0; o >>= 1){ sm += __shfl_xor(sm, o); sq += __shfl_xor(sq, o); }
  if (lane == 0){ red[wave] = sm; red[4 + wave] = sq; }
  __syncthreads();
  float S = red[0] + red[1] + red[2] + red[3];
  float Q = red[4] + red[5] + red[6] + red[7];
  mean = S * (1.0f / 512.0f);
  float var = Q * (1.0f / 512.0f) - mean*mean;
  if (var < 0.f) var = 0.f;
  rstd = rsqrtf(var + 1e-12f);
}

// embeddings LN (float2 vectorized): x,pos f32 -> out bf16 + f32 shadow
__global__ __launch_bounds__(256) void embed_ln(const float* __restrict__ x,
    const float* __restrict__ pos, const float* __restrict__ g,
    const float* __restrict__ bb, ushort* __restrict__ out16, float* __restrict__ out32)
{
  __shared__ float red[8];
  int row = blockIdx.x, tid = threadIdx.x;
  int s = row & (S_ - 1);
  const size_t base = (size_t)row*H_ + tid*2;
  float2 xv = *(const float2*)(x + base);
  float2 pv = *(const float2*)(pos + (size_t)s*H_ + tid*2);
  float v0 = xv.x + pv.x, v1 = xv.y + pv.y;
  float mean, rstd;
  block_ln_stats(v0, v1, red, mean, rstd);
  float2 gv = *(const float2*)(g + tid*2);
  float2 bv = *(const float2*)(bb + tid*2);
  float r0 = (v0 - mean)*rstd*gv.x + bv.x;
  float r1 = (v1 - mean)*rstd*gv.y + bv.y;
  ushort2 o2; o2.x = f2b(r0); o2.y = f2b(r1);
  *(ushort2*)(out16 + base) = o2;
  float2 f2v; f2v.x = r0; f2v.y = r1;
  *(float2*)(out32 + base) = f2v;
}

// LN(t0 + t1 + res32) float2 vectorized
__global__ __launch_bounds__(256) void ln_res(const float* __restrict__ t,
    const float* __restrict__ res, const float* __restrict__ g,
    const float* __restrict__ bb, ushort* __restrict__ out16, float* __restrict__ out32)
{
  __shared__ float red[8];
  int row = blockIdx.x, tid = threadIdx.x;
  const size_t MN = (size_t)M_*H_;
  const size_t base = (size_t)row*H_ + tid*2;
  float2 t0 = *(const float2*)(t + base);
  float2 t1v = *(const float2*)(t + MN + base);
  float2 rv = *(const float2*)(res + base);
  float v0 = t0.x + t1v.x + rv.x;
  float v1 = t0.y + t1v.y + rv.y;
  float mean, rstd;
  block_ln_stats(v0, v1, red, mean, rstd);
  float2 gv = *(const float2*)(g + tid*2);
  float2 bv = *(const float2*)(bb + tid*2);
  float r0 = (v0 - mean)*rstd*gv.x + bv.x;
  float r1 = (v1 - mean)*rstd*gv.y + bv.y;
  ushort2 o2; o2.x = f2b(r0); o2.y = f2b(r1);
  *(ushort2*)(out16 + base) = o2;
  float2 f2v; f2v.x = r0; f2v.y = r1;
  *(float2*)(out32 + base) = f2v;
}

// ---------------------------------------------------------------- attention (MFMA)
// qkv: [B*S][1536] bf16 (q|k|v each 512). Block: 256 thr (4 waves) = one
// (b,h) x 64-row Q-block. Keys/values: 128-wide chunk [s0-32, s0+95].
__global__ __launch_bounds__(256) void attn_mfma(const ushort* __restrict__ qkv,
    const float* __restrict__ mask, ushort* __restrict__ ctx)
{
  __shared__ ushort K_lds[128][72];   // [key c][k]   (pad 72: 2-way free)
  __shared__ ushort Vt[64][136];      // [d][key c]   (pad 136)
  __shared__ ushort P_lds[64][136];   // [q row][key c]
  __shared__ float  kb[128];

  const int tid = threadIdx.x, wave = tid >> 6, lane = tid & 63;
  const int hh = blockIdx.y & (NH_ - 1), b = blockIdx.y >> 3;
  const int s0 = blockIdx.x * 64;
  const size_t rb = (size_t)b * S_;

  // ---- stage K rows c=0..127 and V^T (2 keys/thread, ushort2 transposed writes)
  const int ch = tid & 7;             // 16B chunk within 64-d row
  const int rr = tid >> 3;            // 0..31
  #pragma unroll
  for (int it = 0; it < 2; ++it){
    int c0 = rr*2 + it*64;
    short8v vv[2];
    #pragma unroll
    for (int p = 0; p < 2; ++p){
      int c = c0 + p;
      int j = s0 - 32 + c;
      int jc = min(max(j, 0), S_ - 1);
      const size_t rowb = (rb + jc) * 1536 + hh*64 + ch*8;
      *(short8v*)(&K_lds[c][ch*8]) = *(const short8v*)(qkv + rowb + 512);
      vv[p] = *(const short8v*)(qkv + rowb + 1024);
    }
    #pragma unroll
    for (int t = 0; t < 8; ++t){      // staggered transposed ushort2 writes
      int tt = (t + ch) & 7;
      int d = ch*8 + tt;
      ushort2 w; w.x = (ushort)vv[0][tt]; w.y = (ushort)vv[1][tt];
      *(ushort2*)(&Vt[d][c0]) = w;
    }
  }
  if (tid < 128){
    int j = s0 - 32 + tid;
    kb[tid] = (j >= 0 && j < S_) ? (1.0f - mask[rb + j]) * (-10000.0f) : -1e30f;
  }
  __syncthreads();

  const int wq0 = wave * 16;
  const int lr = lane & 15, lg = lane >> 4, lk = lg * 8;

  // Q fragments (A): row = wq0+lr, k = lk..lk+7 (+32 for second frag)
  const ushort* qbase = qkv + (rb + s0 + wq0 + lr) * 1536 + hh*64;
  short8v aq0 = *(const short8v*)(qbase + lk);
  short8v aq1 = *(const short8v*)(qbase + 32 + lk);

  // scores: 16x128 strip per wave
  f32x4 sacc[8];
  #pragma unroll
  for (int cn = 0; cn < 8; ++cn){
    short8v bk0 = *(const short8v*)(&K_lds[cn*16 + lr][lk]);
    short8v bk1 = *(const short8v*)(&K_lds[cn*16 + lr][32 + lk]);
    f32x4 z = {0.f, 0.f, 0.f, 0.f};
    z = __builtin_amdgcn_mfma_f32_16x16x32_bf16(aq0, bk0, z, 0, 0, 0);
    z = __builtin_amdgcn_mfma_f32_16x16x32_bf16(aq1, bk1, z, 0, 0, 0);
    sacc[cn] = z;
  }

  // row softmax: lane holds cols cn*16+lr of rows wq0 + lg*4 + jr
  #pragma unroll
  for (int jr = 0; jr < 4; ++jr){
    const int R = wq0 + lg*4 + jr;     // row within 64-block
    float v[8], mx = -1e30f;
    #pragma unroll
    for (int cn = 0; cn < 8; ++cn){
      int c = cn*16 + lr;
      float sc = sacc[cn][jr] * 0.125f + kb[c];
      if (c < R || c > R + 64) sc = -1e30f;   // band mask
      v[cn] = sc;
      mx = fmaxf(mx, sc);
    }
    #pragma unroll
    for (int o = 1; o < 16; o <<= 1) mx = fmaxf(mx, __shfl_xor(mx, o));
    float sum = 0.f;
    #pragma unroll
    for (int cn = 0; cn < 8; ++cn){ v[cn] = __expf(v[cn] - mx); sum += v[cn]; }
    #pragma unroll
    for (int o = 1; o < 16; o <<= 1) sum += __shfl_xor(sum, o);
    float qm = mask[rb + s0 + R];
    float inv = ((qm < 0.999f) ? 0.0f : 1.0f) / sum;
    #pragma unroll
    for (int cn = 0; cn < 8; ++cn)
      P_lds[R][cn*16 + lr] = f2b(v[cn] * inv);
  }
  // P write->read is within-wave (rows wq0..wq0+15); LDS ops are in-order per wave.

  // PV: ctx[16x64 strip] = P[16x128] @ V[128x64]
  short8v ap[4];
  #pragma unroll
  for (int ks = 0; ks < 4; ++ks)
    ap[ks] = *(const short8v*)(&P_lds[wq0 + lr][ks*32 + lk]);
  #pragma unroll
  for (int dn = 0; dn < 4; ++dn){
    f32x4 z = {0.f, 0.f, 0.f, 0.f};
    #pragma unroll
    for (int ks = 0; ks < 4; ++ks){
      short8v bv = *(const short8v*)(&Vt[dn*16 + lr][ks*32 + lk]);
      z = __builtin_amdgcn_mfma_f32_16x16x32_bf16(ap[ks], bv, z, 0, 0, 0);
    }
    #pragma unroll
    for (int jr = 0; jr < 4; ++jr){
      int R = wq0 + lg*4 + jr;
      ctx[(rb + s0 + R)*H_ + hh*64 + dn*16 + lr] = f2b(z[jr]);
    }
  }
}

// ---------------------------------------------------------------- pooling
__global__ __launch_bounds__(256) void pool_logit(const ushort* __restrict__ e,
    const float* __restrict__ w2, const float* __restrict__ b2p,
    const float* __restrict__ mask, float* __restrict__ alpha)
{
  int tid = threadIdx.x, wave = tid >> 6, lane = tid & 63;
  int r = blockIdx.x * 4 + wave;
  short8v ev = *(const short8v*)(e + (size_t)r*H_ + lane*8);
  float sacc = 0.f;
  #pragma unroll
  for (int j = 0; j < 8; ++j) sacc += b2f((ushort)ev[j]) * w2[lane*8 + j];
  #pragma unroll
  for (int o = 32; o > 0; o >>= 1) sacc += __shfl_xor(sacc, o);
  if (lane == 0){
    float logit = sacc + b2p[0];
    alpha[r] = __expf(logit) * mask[r];
  }
}

__global__ __launch_bounds__(256) void pool_sum(const float* __restrict__ alpha,
                                                float* __restrict__ invsum)
{
  __shared__ float red[4];
  int b = blockIdx.x, tid = threadIdx.x, wave = tid >> 6, lane = tid & 63;
  float s = 0.f;
  for (int k = tid; k < S_; k += 256) s += alpha[b*S_ + k];
  #pragma unroll
  for (int o = 32; o > 0; o >>= 1) s += __shfl_xor(s, o);
  if (lane == 0) red[wave] = s;
  __syncthreads();
  if (tid == 0) invsum[b] = 1.0f / (red[0] + red[1] + red[2] + red[3] + 1e-8f);
}

// deterministic chunked weighted sum (float2): outacc[chunk][b][h]
__global__ __launch_bounds__(256) void pool_wsum(const float* __restrict__ x,
    const float* __restrict__ alpha, float* __restrict__ out_acc)
{
  int chunk = blockIdx.x, b = blockIdx.y, tid = threadIdx.x;
  int s0 = chunk * 128;
  int c0 = tid * 2;
  float a0 = 0.f, a1 = 0.f;
  for (int i = 0; i < 128; ++i){
    int srow = s0 + i;
    float al = alpha[b*S_ + srow];
    float2 xv = *(const float2*)(x + (size_t)(b*S_ + srow)*H_ + c0);
    a0 += xv.x * al;
    a1 += xv.y * al;
  }
  float2 o; o.x = a0; o.y = a1;
  *(float2*)(out_acc + (size_t)chunk*B_*H_ + b*H_ + c0) = o;
}

__global__ __launch_bounds__(256) void pool_final(const float* __restrict__ out_acc,
    const float* __restrict__ invsum, float* __restrict__ out)
{
  int i = blockIdx.x * 256 + threadIdx.x;
  if (i < B_*H_){
    int b = i >> 9;
    float s = 0.f;
    #pragma unroll
    for (int c = 0; c < 16; ++c) s += out_acc[(size_t)c*B_*H_ + i];
    out[i] = s * invsum[b];
  }
}

// ---------------------------------------------------------------- launch
extern "C" void kernel_launch(void* const* d_in, const int* in_sizes, int n_in,
                              void* d_out, int out_size, void* d_ws, size_t ws_size,
                              hipStream_t stream)
{
  const float* input_embs = (const float*)d_in[0];
  const float* mask       = (const float*)d_in[1];
  const float* pos        = (const float*)d_in[2];
  const float* ln_emb_g   = (const float*)d_in[3];
  const float* ln_emb_b   = (const float*)d_in[4];
  const float* Wq  = (const float*)d_in[5];
  const float* bq  = (const float*)d_in[6];
  const float* Wk  = (const float*)d_in[7];
  const float* bk  = (const float*)d_in[8];
  const float* Wv  = (const float*)d_in[9];
  const float* bv  = (const float*)d_in[10];
  const float* Wo  = (const float*)d_in[11];
  const float* bo  = (const float*)d_in[12];
  const float* ln1_g = (const float*)d_in[13];
  const float* ln1_b = (const float*)d_in[14];
  const float* Wi  = (const float*)d_in[15];
  const float* bi  = (const float*)d_in[16];
  const float* Wo2 = (const float*)d_in[17];
  const float* bo2 = (const float*)d_in[18];
  const float* ln2_g = (const float*)d_in[19];
  const float* ln2_b = (const float*)d_in[20];
  const float* pW1 = (const float*)d_in[21];
  const float* pb1 = (const float*)d_in[22];
  const float* pW2 = (const float*)d_in[23];
  const float* pb2 = (const float*)d_in[24];

  char* ws = (char*)d_ws;
  size_t off = 0;
  auto alloc = [&](size_t bytes)->char*{
    char* p = ws + off; off += (bytes + 255) & ~(size_t)255; return p;
  };
  ushort* WqkvT  = (ushort*)alloc((size_t)L_*1536*512*2);
  ushort* WoT    = (ushort*)alloc((size_t)L_*512*512*2);
  ushort* WiT    = (ushort*)alloc((size_t)L_*2048*512*2);
  ushort* Wo2T   = (ushort*)alloc((size_t)L_*512*2048*2);
  ushort* pW1T   = (ushort*)alloc((size_t)512*512*2);
  float*  bqkv   = (float*)alloc((size_t)L_*1536*4);
  ushort* h16    = (ushort*)alloc((size_t)M_*H_*2);
  float*  h32    = (float*)alloc((size_t)M_*H_*4);
  ushort* qkv    = (ushort*)alloc((size_t)M_*1536*2);
  ushort* ctx    = (ushort*)alloc((size_t)M_*H_*2);
  ushort* attn16 = (ushort*)alloc((size_t)M_*H_*2);
  float*  attn32 = (float*)alloc((size_t)M_*H_*4);
  ushort* inter  = (ushort*)alloc((size_t)M_*INTER_*2);
  float*  t1     = (float*)alloc((size_t)2*M_*H_*4);   // 2 split-K partials
  float*  alpha  = (float*)alloc((size_t)M_*4);
  float*  invsum = (float*)alloc(256);
  float*  outacc = (float*)alloc((size_t)16*B_*H_*4);

  dim3 tb(256);
  TPack tp;
  tp.wq = Wq; tp.wk = Wk; tp.wv = Wv; tp.wo = Wo; tp.pw1 = pW1;
  tp.wqkvT = WqkvT; tp.woT = WoT; tp.pw1T = pW1T;
  transpose512_all<<<dim3(16,16,17), tb, 0, stream>>>(tp);
  transpose_k<<<dim3(64,16,L_), tb, 0, stream>>>(Wi, WiT,    512, 2048, (size_t)512*2048, (size_t)2048*512);
  transpose_k<<<dim3(16,64,L_), tb, 0, stream>>>(Wo2, Wo2T, 2048,  512, (size_t)2048*512, (size_t)512*2048);
  pack_bqkv<<<dim3(L_*1536/256), tb, 0, stream>>>(bq, bk, bv, bqkv);

  embed_ln<<<dim3(M_), tb, 0, stream>>>(input_embs, pos, ln_emb_g, ln_emb_b, h16, h32);

  for (int l = 0; l < L_; ++l){
    gemm_bt<0,64><<<dim3(12,64,1), tb, 0, stream>>>(h16, WqkvT + (size_t)l*1536*512, bqkv + l*1536,
                                                    qkv, nullptr, M_, 1536, 512, 512);
    attn_mfma<<<dim3(S_/64, B_*NH_), tb, 0, stream>>>(qkv, mask, ctx);
    gemm_bt<3,64><<<dim3(4,64,2), tb, 0, stream>>>(ctx, WoT + (size_t)l*512*512, bo + l*512,
                                                   nullptr, t1, M_, 512, 512, 256);
    ln_res<<<dim3(M_), tb, 0, stream>>>(t1, h32, ln1_g + l*512, ln1_b + l*512, attn16, attn32);
    gemm_bt<1,128><<<dim3(16,32,1), tb, 0, stream>>>(attn16, WiT + (size_t)l*2048*512, bi + l*2048,
                                                     inter, nullptr, M_, 2048, 512, 512);
    gemm_bt<3,64><<<dim3(4,64,2), tb, 0, stream>>>(inter, Wo2T + (size_t)l*512*2048, bo2 + l*512,
                                                   nullptr, t1, M_, 512, 2048, 1024);
    ln_res<<<dim3(M_), tb, 0, stream>>>(t1, attn32, ln2_g + l*512, ln2_b + l*512, h16, h32);
  }

  // pooling: e = tanh(h @ pW1 + pb1)  (reuse ctx buffer for e)
  gemm_bt<2,64><<<dim3(4,64,1), tb, 0, stream>>>(h16, pW1T, pb1, ctx, nullptr, M_, 512, 512, 512);
  pool_logit<<<dim3(M_/4), tb, 0, stream>>>(ctx, pW2, pb2, mask, alpha);
  pool_sum<<<dim3(B_), tb, 0, stream>>>(alpha, invsum);
  pool_wsum<<<dim3(16, B_), tb, 0, stream>>>(h32, alpha, outacc);
  pool_final<<<dim3((B_*H_ + 255)/256), tb, 0, stream>>>(outacc, invsum, (float*)d_out);
}